// Round 5
// baseline (2022.107 us; speedup 1.0000x reference)
//
#include <hip/hip_runtime.h>
#include <math.h>

// ============================================================================
// VL_SAE: N=4096, D=768, H=16384, topk=32
// Round 8: Round 6/7 resubmission. Both failures had NO timing block =>
//   container died during setup (infra), not in our code. Hardening anyway:
//   - fallback_kernel no longer uses a 64 KB LDS sim cache; it writes dense
//     sims to the row's latent slice (global, already zeroed) and
//     radix-selects from there (proven legacy_select pattern, ~4 KB LDS).
// Round 6/7:
//   - KILL THE DENSE LATENT ROUND TRIP. sim = 2-sqrt(2-2cos) >= 0 and
//     monotone in cos => top-k by |sim| == top-k by cos. GEMM epilogue
//     appends candidates with cos >= THR_COS (~220/row of 16384) to
//     per-row lists instead of writing 512 MB dense sim. cand_select
//     scatters the ~32 keeps into the zeroed latent. Removes ~1.5 GB
//     of HBM traffic (dense write + re-read + zero-write).
//   - Safety is deterministic: per row cand_select certifies
//     (cnt<=CCAP && cnt>=33 && v*-MARGIN > THR_SIM_GUARD); else flags the
//     row for exact fp32 dense recompute + radix-exact top-k.
//   - GEMM core = Round-4 structure (48 KB dbuf, vmcnt(6), 2 barriers/K-step,
//     bounds(256,3)) -- measured best (641 us vs 689 for 3-buf round 5).
//   - zero_fill_kernel (capture-safe) zeroes latent + cand_cnt/flag.
//   - Candidate buffers alias the WvT region (dead before transpose runs).
// Round 4 (kept): counted-vmcnt pipeline, setprio, XCD swizzle.
// Round 3 (kept): 2-product bf16 split GEMM, MARGIN classify + exact refine.
// ============================================================================

#define N_ROWS 4096
#define D_DIM  768
#define H_DIM  16384
#define M_TOT  8192
#define TOPK   32
#define MARGIN 1e-3f
#define SEL_CAP 40
#define AMB_CAP 64
#define CCAP   512
// cos filter: ~2.2 sigma (sigma = 1/sqrt(768) = 0.036). Row 33rd-largest
// cos ~ 0.104 (2.9 sigma). sim(0.08) = 2 - sqrt(1.84) = 0.643534.
#define THR_COS 0.08f
#define THR_SIM_GUARD 0.6436f

typedef __attribute__((ext_vector_type(8))) short short8;
typedef __attribute__((ext_vector_type(4))) float floatx4;

__device__ inline unsigned short bf16_rne(float f) {
    unsigned u = __float_as_uint(f);
    unsigned r = u + 0x7fffu + ((u >> 16) & 1u);
    return (unsigned short)(r >> 16);
}

__device__ inline void gload16(const unsigned short* g, unsigned short* l) {
    __builtin_amdgcn_global_load_lds(
        (const __attribute__((address_space(1))) void*)g,
        (__attribute__((address_space(3))) void*)l, 16, 0, 0);
}

// ---------------------------------------------------------------------------
// capture-safe zeroing: latent (128M floats) + cand_cnt/flag (2*M_TOT ints)
__global__ __launch_bounds__(256)
void zero_fill_kernel(floatx4* __restrict__ lat4, long n4,
                      int* __restrict__ cnts, int ncnt)
{
    long i = (long)blockIdx.x * 256 + threadIdx.x;
    long stride = (long)gridDim.x * 256;
    floatx4 z = (floatx4){0.f, 0.f, 0.f, 0.f};
    for (long p = i; p < n4; p += stride)
        __builtin_nontemporal_store(z, &lat4[p]);
    for (long p = i; p < ncnt; p += stride)
        cnts[p] = 0;
}

// ---------------------------------------------------------------------------
// normalize rows of embv/embt/enc; emb -> bf16 hi+lo, enc -> bf16 hi only
__global__ void split_all_kernel(const float* __restrict__ embv,
                                 const float* __restrict__ embt,
                                 const float* __restrict__ enc,
                                 unsigned short* __restrict__ Ahi,
                                 unsigned short* __restrict__ Alo,
                                 unsigned short* __restrict__ Bh,
                                 float* __restrict__ invA,
                                 float* __restrict__ invB)
{
    int row = blockIdx.x;                  // 0..2N+H-1
    int tid = threadIdx.x;
    const float* src;
    unsigned short *hi, *lo;
    float* invp;
    if (row < N_ROWS) {
        src = embv + (size_t)row * D_DIM;
        hi = Ahi + (size_t)row * D_DIM; lo = Alo + (size_t)row * D_DIM;
        invp = invA + row;
    } else if (row < 2 * N_ROWS) {
        int r = row - N_ROWS;
        src = embt + (size_t)r * D_DIM;
        hi = Ahi + (size_t)row * D_DIM; lo = Alo + (size_t)row * D_DIM;
        invp = invA + row;
    } else {
        int r = row - 2 * N_ROWS;
        src = enc + (size_t)r * D_DIM;
        hi = Bh + (size_t)r * D_DIM; lo = nullptr;
        invp = invB + r;
    }
    __shared__ float red[4];
    const float4* s4 = reinterpret_cast<const float4*>(src);
    float4 v = make_float4(0.f, 0.f, 0.f, 0.f);
    float ss = 0.f;
    if (tid < 192) {
        v = s4[tid];
        ss = v.x * v.x + v.y * v.y + v.z * v.z + v.w * v.w;
    }
    #pragma unroll
    for (int o = 32; o > 0; o >>= 1) ss += __shfl_down(ss, o);
    int wave = tid >> 6, lane = tid & 63;
    if (lane == 0) red[wave] = ss;
    __syncthreads();
    if (tid == 0) {
        float tot = red[0] + red[1] + red[2];
        red[0] = 1.f / fmaxf(sqrtf(tot), 1e-12f);
    }
    __syncthreads();
    float inv = red[0];
    if (tid == 0) *invp = inv;
    if (tid < 192) {
        float x[4] = {v.x * inv, v.y * inv, v.z * inv, v.w * inv};
        unsigned short hh[4], ll[4];
        #pragma unroll
        for (int t = 0; t < 4; t++) {
            hh[t] = bf16_rne(x[t]);
            float hf = __uint_as_float((unsigned)hh[t] << 16);
            ll[t] = bf16_rne(x[t] - hf);
        }
        ushort4 h4; h4.x = hh[0]; h4.y = hh[1]; h4.z = hh[2]; h4.w = hh[3];
        *reinterpret_cast<ushort4*>(hi + tid * 4) = h4;
        if (lo) {
            ushort4 l4; l4.x = ll[0]; l4.y = ll[1]; l4.z = ll[2]; l4.w = ll[3];
            *reinterpret_cast<ushort4*>(lo + tid * 4) = l4;
        }
    }
}

// ---------------------------------------------------------------------------
// 2-product split GEMM: cos = (Ahi+Alo) . Bh  (inputs pre-normalized)
// Round-4 pipeline core; candidate-filter epilogue (no dense write).
#define GBK 32
#define NTILE (D_DIM / GBK)   // 24

__global__ __launch_bounds__(256, 3)
void gemm_mfma_kernel(const unsigned short* __restrict__ Ahi,
                      const unsigned short* __restrict__ Alo,
                      const unsigned short* __restrict__ Bh,
                      int* __restrict__ cand_cnt,
                      int* __restrict__ cand_idx,
                      float* __restrict__ cand_val)
{
    __shared__ unsigned short sA[2][2][128 * GBK];
    __shared__ unsigned short sB[2][128 * GBK];

    int tid = threadIdx.x;
    int lane = tid & 63;
    int wave = tid >> 6;
    int wr = (wave >> 1) * 64;
    int wc = (wave & 1) * 64;
    int m = lane & 15;
    int q = lane >> 4;

    // XCD-aware bijective swizzle: grid = 128x64 = 8192 blocks, 8192 % 8 == 0.
    unsigned nwgx = gridDim.x;                        // 128
    unsigned lid = blockIdx.y * nwgx + blockIdx.x;
    unsigned cpx = (nwgx * gridDim.y) >> 3;           // 1024
    unsigned swz = (lid & 7u) * cpx + (lid >> 3);
    int bx = (int)(swz % nwgx);
    int by = (int)(swz / nwgx);

    int row0 = by * 128;
    int col0 = bx * 128;

    int p0 = tid, p1 = tid + 256;
    int r0 = ((p0 >> 5) << 3) | (p0 & 7), q0 = (p0 >> 3) & 3;
    int r1 = ((p1 >> 5) << 3) | (p1 & 7), q1 = (p1 >> 3) & 3;
    size_t aoff0 = (size_t)(row0 + r0) * D_DIM + q0 * 8;
    size_t aoff1 = (size_t)(row0 + r1) * D_DIM + q1 * 8;
    size_t boff0 = (size_t)(col0 + r0) * D_DIM + q0 * 8;
    size_t boff1 = (size_t)(col0 + r1) * D_DIM + q1 * 8;

    int am0 = wr + m;
    int bn0 = wc + m;
    int offA = ((am0 >> 3) << 8) + (q << 6) + ((am0 & 7) << 3);
    int offB = ((bn0 >> 3) << 8) + (q << 6) + ((bn0 & 7) << 3);

    floatx4 acc[4][4];
    #pragma unroll
    for (int i = 0; i < 4; i++)
        #pragma unroll
        for (int j = 0; j < 4; j++)
            acc[i][j] = (floatx4){0.f, 0.f, 0.f, 0.f};

    // 6 global_load_lds per stage (vmcnt unit)
    auto stage = [&](int t, int b) {
        int k0 = t * GBK;
        gload16(Ahi + aoff0 + k0, &sA[b][0][p0 * 8]);
        gload16(Ahi + aoff1 + k0, &sA[b][0][p1 * 8]);
        gload16(Alo + aoff0 + k0, &sA[b][1][p0 * 8]);
        gload16(Alo + aoff1 + k0, &sA[b][1][p1 * 8]);
        gload16(Bh + boff0 + k0, &sB[b][p0 * 8]);
        gload16(Bh + boff1 + k0, &sB[b][p1 * 8]);
    };

    auto compute = [&](int b) {
        short8 fah[4], fal[4], fbv[4];
        #pragma unroll
        for (int i = 0; i < 4; i++) {
            fah[i] = *(const short8*)&sA[b][0][offA + i * 512];
            fal[i] = *(const short8*)&sA[b][1][offA + i * 512];
        }
        #pragma unroll
        for (int j = 0; j < 4; j++)
            fbv[j] = *(const short8*)&sB[b][offB + j * 512];
        __builtin_amdgcn_s_setprio(1);
        #pragma unroll
        for (int j = 0; j < 4; j++) {
            #pragma unroll
            for (int i = 0; i < 4; i++) {
                acc[i][j] = __builtin_amdgcn_mfma_f32_16x16x32_bf16(fah[i], fbv[j], acc[i][j], 0, 0, 0);
                acc[i][j] = __builtin_amdgcn_mfma_f32_16x16x32_bf16(fal[i], fbv[j], acc[i][j], 0, 0, 0);
            }
        }
        __builtin_amdgcn_s_setprio(0);
    };

    // Round-4 pipeline: depth-1 dbuf, vmcnt(6) (tile t retires, t+1 stays in
    // flight), 2 barriers/K-step. Measured best (641 us vs 689 for 3-buf).
    stage(0, 0);
    int cur = 0;
    for (int t = 0; t < NTILE - 1; ++t) {
        stage(t + 1, cur ^ 1);
        asm volatile("s_waitcnt vmcnt(6)" ::: "memory");
        __builtin_amdgcn_s_barrier();
        __builtin_amdgcn_sched_barrier(0);
        compute(cur);
        __builtin_amdgcn_sched_barrier(0);
        __builtin_amdgcn_s_barrier();
        cur ^= 1;
    }
    asm volatile("s_waitcnt vmcnt(0)" ::: "memory");
    __builtin_amdgcn_s_barrier();
    __builtin_amdgcn_sched_barrier(0);
    compute(cur);

    // Epilogue: candidate filter. ~228 appends per block (vs 16384 stores).
    // Overflow (slot >= CCAP) leaves cnt > CCAP -> row flagged for fallback.
    #pragma unroll
    for (int i = 0; i < 4; i++) {
        #pragma unroll
        for (int r = 0; r < 4; r++) {
            int grow = row0 + wr + i * 16 + q * 4 + r;
            #pragma unroll
            for (int j = 0; j < 4; j++) {
                float cosv = acc[i][j][r];
                if (cosv >= THR_COS) {
                    int slot = atomicAdd(&cand_cnt[grow], 1);
                    if (slot < CCAP) {
                        cand_idx[(size_t)grow * CCAP + slot] = col0 + wc + m + j * 16;
                        cand_val[(size_t)grow * CCAP + slot] = cosv;
                    }
                }
            }
        }
    }
}

// ---------------------------------------------------------------------------
// Per-row select over the candidate list (~220 entries). Same proven
// MARGIN classify as round 3; flags row for exact fallback if the static
// filter cannot be certified for this row.
__global__ __launch_bounds__(256)
void cand_select_kernel(const int* __restrict__ cand_cnt,
                        const int* __restrict__ cand_idx,
                        const float* __restrict__ cand_val,
                        float* __restrict__ latent,
                        int* __restrict__ sel_cnt,
                        int* __restrict__ sel_idx,
                        float* __restrict__ sel_val,
                        int* __restrict__ amb_cnt,
                        int* __restrict__ amb_idx,
                        int* __restrict__ flag)
{
    int row = blockIdx.x;
    int tid = threadIdx.x;
    int cnt = cand_cnt[row];

    __shared__ float sv[CCAP];
    __shared__ int   si[CCAP];
    __shared__ int svstar, skept, samb;

    if (cnt > CCAP || cnt < TOPK + 1) {          // overflow or too few: exact path
        if (tid == 0) { flag[row] = 1; sel_cnt[row] = 0; amb_cnt[row] = 0; }
        return;
    }
    for (int c = tid; c < cnt; c += 256) {
        float cosv = cand_val[(size_t)row * CCAP + c];
        sv[c] = 2.f - sqrtf(fmaxf(2.f - 2.f * cosv, 0.f));   // same fp32 ops as before
        si[c] = cand_idx[(size_t)row * CCAP + c];
    }
    if (tid == 0) { svstar = 0x7FFFFFFF; skept = 0; samb = 0; }
    __syncthreads();

    // v* = 33rd largest candidate sim (== 33rd largest overall, since all
    // candidates >= every non-candidate and cnt >= 33). Slot-order tie-break;
    // ties land in the ambiguous band and are refined exactly.
    for (int c = tid; c < cnt; c += 256) {
        float a = sv[c];
        int g = 0;
        for (int j = 0; j < cnt; j++) {
            float aj = sv[j];
            g += (aj > a || (aj == a && j < c)) ? 1 : 0;
        }
        if (g <= TOPK) atomicMin(&svstar, __float_as_int(a));
    }
    __syncthreads();
    float vs = __int_as_float(svstar);

    // Certify the static filter: every non-candidate has approx sim <
    // THR_SIM_GUARD < vs - MARGIN  =>  certain drop under the round-3 rule.
    if (vs - MARGIN <= THR_SIM_GUARD) {
        if (tid == 0) { flag[row] = 1; sel_cnt[row] = 0; amb_cnt[row] = 0; }
        return;
    }

    for (int c = tid; c < cnt; c += 256) {
        float f = sv[c];
        int idx = si[c];
        if (f > vs + MARGIN) {
            int s = atomicAdd(&skept, 1);
            sel_idx[(size_t)row * SEL_CAP + s] = idx;
            sel_val[(size_t)row * SEL_CAP + s] = f;
            latent[(size_t)row * H_DIM + idx] = f;
        } else if (f >= vs - MARGIN) {
            int s = atomicAdd(&samb, 1);
            if (s < AMB_CAP) amb_idx[(size_t)row * AMB_CAP + s] = idx;
        }
    }
    __syncthreads();
    if (tid == 0) { sel_cnt[row] = skept; amb_cnt[row] = min(samb, AMB_CAP); }
}

// ---------------------------------------------------------------------------
// Exact fallback for flagged rows: dense fp32 recompute into the row's
// latent slice (global scratch, already zeroed), then radix-exact
// top-(k+1) threshold + strictly-greater keep (kthvalue semantics),
// zeroing dropped entries. ~4 KB LDS. Expected 0 rows; correctness net.
__global__ __launch_bounds__(256)
void fallback_kernel(const int* __restrict__ flag,
                     const float* __restrict__ embv,
                     const float* __restrict__ embt,
                     const float* __restrict__ enc,
                     const float* __restrict__ invA,
                     const float* __restrict__ invB,
                     float* __restrict__ latent,
                     int* __restrict__ sel_cnt,
                     int* __restrict__ sel_idx,
                     float* __restrict__ sel_val,
                     int* __restrict__ amb_cnt)
{
    int row = blockIdx.x;
    if (!flag[row]) return;
    int tid = threadIdx.x;
    float* v = latent + (size_t)row * H_DIM;
    __shared__ float ssrc[D_DIM];
    __shared__ unsigned hist[256];
    __shared__ unsigned s_prefix;
    __shared__ int s_k, s_cnt;

    const float* src = (row < N_ROWS) ? embv + (size_t)row * D_DIM
                                      : embt + (size_t)(row - N_ROWS) * D_DIM;
    for (int d = tid; d < D_DIM; d += 256) ssrc[d] = src[d];
    float ia = invA[row];
    __syncthreads();
    for (int h = tid; h < H_DIM; h += 256) {
        const float* w = enc + (size_t)h * D_DIM;
        float d = 0.f;
        for (int t = 0; t < D_DIM; t++) d += ssrc[t] * w[t];
        float cosv = d * ia * invB[h];
        v[h] = 2.f - sqrtf(fmaxf(2.f - 2.f * cosv, 0.f));
    }
    __syncthreads();

    // radix-select the 33rd largest (sims >= 0 -> raw bits are monotone)
    int k = TOPK + 1;
    unsigned prefix = 0;
    for (int shift = 24; shift >= 0; shift -= 8) {
        hist[tid] = 0;
        __syncthreads();
        unsigned pmask = (shift == 24) ? 0u : (0xFFFFFFFFu << (shift + 8));
        for (int i = tid; i < H_DIM; i += 256) {
            unsigned u = __float_as_uint(v[i]);
            if ((u & pmask) == prefix)
                atomicAdd(&hist[(u >> shift) & 255u], 1u);
        }
        __syncthreads();
        if (tid == 0) {
            int c = 0, b = 255;
            for (; b >= 0; b--) {
                c += (int)hist[b];
                if (c >= k) break;
            }
            if (b < 0) b = 0;
            s_prefix = prefix | ((unsigned)b << shift);
            s_k = k - (c - (int)hist[b]);
        }
        __syncthreads();
        prefix = s_prefix;
        k = s_k;
        __syncthreads();
    }
    float thres = __uint_as_float(prefix);
    if (tid == 0) s_cnt = 0;
    __syncthreads();
    for (int i = tid; i < H_DIM; i += 256) {
        float x = v[i];
        bool keep = (x > thres);
        v[i] = keep ? x : 0.f;
        if (keep) {
            int slot = atomicAdd(&s_cnt, 1);
            if (slot < SEL_CAP) {
                sel_idx[(size_t)row * SEL_CAP + slot] = i;
                sel_val[(size_t)row * SEL_CAP + slot] = x;
            }
        }
    }
    __syncthreads();
    if (tid == 0) {
        sel_cnt[row] = (s_cnt > SEL_CAP) ? SEL_CAP : s_cnt;
        amb_cnt[row] = 0;
    }
}

// ---------------------------------------------------------------------------
// exact fp32 recompute for ambiguous entries; tie-aware np-exact top-off
__global__ void refine_kernel(const float* __restrict__ embv,
                              const float* __restrict__ embt,
                              const float* __restrict__ enc,
                              const float* __restrict__ invA,
                              const float* __restrict__ invB,
                              float* __restrict__ latent,
                              int* __restrict__ sel_cnt,
                              int* __restrict__ sel_idx,
                              float* __restrict__ sel_val,
                              const int* __restrict__ amb_cnt,
                              const int* __restrict__ amb_idx)
{
    int row = blockIdx.x;
    int s = amb_cnt[row];
    if (s == 0) return;
    int tid = threadIdx.x;
    int m = sel_cnt[row];
    int need = TOPK - m;
    float* v = latent + (size_t)row * H_DIM;
    if (need <= 0) return;                 // ambiguous slots already zero
    __shared__ float ex[AMB_CAP];
    __shared__ int evs, kc;
    const float* src = (row < N_ROWS) ? embv + (size_t)row * D_DIM
                                      : embt + (size_t)(row - N_ROWS) * D_DIM;
    float ia = invA[row];
    int wave = tid >> 6, lane = tid & 63;
    for (int a = wave; a < s; a += 4) {
        int h = amb_idx[(size_t)row * AMB_CAP + a];
        const float* w = enc + (size_t)h * D_DIM;
        float d = 0.f;
        for (int t = lane; t < D_DIM; t += 64) d += src[t] * w[t];
        #pragma unroll
        for (int o = 32; o > 0; o >>= 1) d += __shfl_down(d, o);
        if (lane == 0) {
            float cosv = d * ia * invB[h];
            ex[a] = 2.f - sqrtf(fmaxf(2.f - 2.f * cosv, 0.f));
        }
    }
    if (tid == 0) { evs = 0x7FFFFFFF; kc = 0; }
    __syncthreads();
    if (tid < s) {
        float mya = fabsf(ex[tid]);
        int g = 0;
        for (int j = 0; j < s; j++) {
            float aj = fabsf(ex[j]);
            g += (aj > mya || (aj == mya && j < tid)) ? 1 : 0;
        }
        if (g <= need) atomicMin(&evs, __float_as_int(mya));
    }
    __syncthreads();
    float ep = __int_as_float(evs);
    if (tid < s) {
        int idx = amb_idx[(size_t)row * AMB_CAP + tid];
        float e = ex[tid];
        if (fabsf(e) > ep) {
            int sl = atomicAdd(&kc, 1);
            v[idx] = e;
            sel_idx[(size_t)row * SEL_CAP + m + sl] = idx;
            sel_val[(size_t)row * SEL_CAP + m + sl] = e;
        }
    }
    __syncthreads();
    if (tid == 0) sel_cnt[row] = m + kc;
}

// ---------------------------------------------------------------------------
__global__ void transpose_kernel(const float* __restrict__ Wv,
                                 const float* __restrict__ Wt,
                                 float* __restrict__ WvT,
                                 float* __restrict__ WtT)
{
    int z = blockIdx.z;
    const float* W = z ? Wt : Wv;
    float* WT = z ? WtT : WvT;
    __shared__ float tile[32][33];
    int tx = threadIdx.x & 31;
    int ty = threadIdx.x >> 5;
    int h0 = blockIdx.x * 32;
    int d0 = blockIdx.y * 32;
    #pragma unroll
    for (int t = 0; t < 4; t++)
        tile[ty + t * 8][tx] = W[(size_t)(d0 + ty + t * 8) * H_DIM + h0 + tx];
    __syncthreads();
    #pragma unroll
    for (int t = 0; t < 4; t++)
        WT[(size_t)(h0 + ty + t * 8) * D_DIM + d0 + tx] = tile[tx][ty + t * 8];
}

// ---------------------------------------------------------------------------
__global__ void recon_kernel(const float* __restrict__ Wv_,
                             const float* __restrict__ Wt_,
                             const float* __restrict__ bv,
                             const float* __restrict__ bt,
                             const int* __restrict__ sel_cnt,
                             const int* __restrict__ sel_idx,
                             const float* __restrict__ sel_val,
                             long sh, long sd,
                             float* __restrict__ out)
{
    int n = blockIdx.x;
    int z = blockIdx.y;
    int row = z * N_ROWS + n;
    const float* W = z ? Wt_ : Wv_;
    const float* bias = z ? bt : bv;
    float* o = out + (size_t)z * N_ROWS * D_DIM + (size_t)n * D_DIM;

    __shared__ int s_idx[SEL_CAP];
    __shared__ float s_val[SEL_CAP];
    __shared__ int s_cnt;
    int tid = threadIdx.x;
    if (tid == 0) s_cnt = sel_cnt[row];
    __syncthreads();
    int cnt = s_cnt;
    if (tid < cnt) {
        s_idx[tid] = sel_idx[(size_t)row * SEL_CAP + tid];
        s_val[tid] = sel_val[(size_t)row * SEL_CAP + tid];
    }
    __syncthreads();

    for (int d = tid; d < D_DIM; d += 256) {
        float acc = bias[d];
        for (int j = 0; j < cnt; j++)
            acc += s_val[j] * W[(size_t)s_idx[j] * sh + (size_t)d * sd];
        o[d] = acc;
    }
}

// ============================ LEGACY FALLBACK ==============================
__global__ void row_invnorm_kernel(const float* __restrict__ x,
                                   float* __restrict__ inv, int rows) {
    int row = blockIdx.x * 4 + (threadIdx.x >> 6);
    int lane = threadIdx.x & 63;
    if (row >= rows) return;
    const float4* p = reinterpret_cast<const float4*>(x + (size_t)row * D_DIM);
    float ss = 0.f;
    #pragma unroll
    for (int i = 0; i < 3; i++) {
        float4 v = p[lane + i * 64];
        ss += v.x * v.x + v.y * v.y + v.z * v.z + v.w * v.w;
    }
    #pragma unroll
    for (int off = 32; off > 0; off >>= 1) ss += __shfl_down(ss, off);
    if (lane == 0) inv[row] = 1.f / fmaxf(sqrtf(ss), 1e-12f);
}

#define BM 128
#define BN 128
#define BK 16
__global__ __launch_bounds__(256)
void gemm_sim_kernel(const float* __restrict__ embv,
                     const float* __restrict__ embt,
                     const float* __restrict__ enc,
                     const float* __restrict__ inv_emb,
                     const float* __restrict__ inv_enc,
                     float* __restrict__ latent)
{
    int z = blockIdx.z;
    const float* A = z ? embt : embv;
    const float* invA = inv_emb + z * N_ROWS;
    float* C = latent + (size_t)z * N_ROWS * H_DIM;
    __shared__ float As[BK][BM + 4];
    __shared__ float Bs[BK][BN + 4];
    int tid = threadIdx.x;
    int tx = tid & 15, ty = tid >> 4;
    int row0 = blockIdx.y * BM, col0 = blockIdx.x * BN;
    float acc[8][8];
    #pragma unroll
    for (int i = 0; i < 8; i++)
        #pragma unroll
        for (int j = 0; j < 8; j++) acc[i][j] = 0.f;
    for (int k0 = 0; k0 < D_DIM; k0 += BK) {
        #pragma unroll
        for (int t = 0; t < 2; t++) {
            int idx = t * 256 + tid;
            int r = idx >> 2, c4 = idx & 3;
            float4 va = *reinterpret_cast<const float4*>(
                A + (size_t)(row0 + r) * D_DIM + k0 + c4 * 4);
            As[c4 * 4 + 0][r] = va.x; As[c4 * 4 + 1][r] = va.y;
            As[c4 * 4 + 2][r] = va.z; As[c4 * 4 + 3][r] = va.w;
            float4 vb = *reinterpret_cast<const float4*>(
                enc + (size_t)(col0 + r) * D_DIM + k0 + c4 * 4);
            Bs[c4 * 4 + 0][r] = vb.x; Bs[c4 * 4 + 1][r] = vb.y;
            Bs[c4 * 4 + 2][r] = vb.z; Bs[c4 * 4 + 3][r] = vb.w;
        }
        __syncthreads();
        #pragma unroll
        for (int kk = 0; kk < BK; kk++) {
            float a[8], b[8];
            *reinterpret_cast<float4*>(&a[0]) = *reinterpret_cast<const float4*>(&As[kk][ty * 8]);
            *reinterpret_cast<float4*>(&a[4]) = *reinterpret_cast<const float4*>(&As[kk][ty * 8 + 4]);
            *reinterpret_cast<float4*>(&b[0]) = *reinterpret_cast<const float4*>(&Bs[kk][tx * 8]);
            *reinterpret_cast<float4*>(&b[4]) = *reinterpret_cast<const float4*>(&Bs[kk][tx * 8 + 4]);
            #pragma unroll
            for (int i = 0; i < 8; i++)
                #pragma unroll
                for (int j = 0; j < 8; j++)
                    acc[i][j] = fmaf(a[i], b[j], acc[i][j]);
        }
        __syncthreads();
    }
    #pragma unroll
    for (int i = 0; i < 8; i++) {
        int n = row0 + ty * 8 + i;
        float sa = invA[n];
        float* Crow = C + (size_t)n * H_DIM + col0 + tx * 8;
        float tmp[8];
        #pragma unroll
        for (int j = 0; j < 8; j++) {
            float cosv = acc[i][j] * sa * inv_enc[col0 + tx * 8 + j];
            tmp[j] = 2.f - sqrtf(fmaxf(2.f - 2.f * cosv, 0.f));
        }
        float4 o0 = {tmp[0], tmp[1], tmp[2], tmp[3]};
        float4 o1 = {tmp[4], tmp[5], tmp[6], tmp[7]};
        *reinterpret_cast<float4*>(Crow) = o0;
        *reinterpret_cast<float4*>(Crow + 4) = o1;
    }
}

__global__ void legacy_select_kernel(float* __restrict__ latent,
                                     const int* __restrict__ topk_p,
                                     int* __restrict__ sel_cnt,
                                     int* __restrict__ sel_idx,
                                     float* __restrict__ sel_val)
{
    int row = blockIdx.x;
    float* v = latent + (size_t)row * H_DIM;
    int tid = threadIdx.x;
    __shared__ unsigned hist[256];
    __shared__ unsigned s_prefix;
    __shared__ int s_k;
    __shared__ int s_cnt;
    int k = topk_p[0] + 1;
    unsigned prefix = 0;
    for (int shift = 24; shift >= 0; shift -= 8) {
        hist[tid] = 0;
        __syncthreads();
        unsigned pmask = (shift == 24) ? 0u : (0xFFFFFFFFu << (shift + 8));
        for (int i = tid; i < H_DIM; i += 256) {
            unsigned u = __float_as_uint(v[i]) & 0x7FFFFFFFu;
            if ((u & pmask) == prefix)
                atomicAdd(&hist[(u >> shift) & 255u], 1u);
        }
        __syncthreads();
        if (tid == 0) {
            int c = 0, b = 255;
            for (; b >= 0; b--) {
                c += (int)hist[b];
                if (c >= k) break;
            }
            if (b < 0) b = 0;
            s_prefix = prefix | ((unsigned)b << shift);
            s_k = k - (c - (int)hist[b]);
        }
        __syncthreads();
        prefix = s_prefix;
        k = s_k;
        __syncthreads();
    }
    float thres = __uint_as_float(prefix);
    if (tid == 0) s_cnt = 0;
    __syncthreads();
    for (int i = tid; i < H_DIM; i += 256) {
        float x = v[i];
        bool keep = (fabsf(x) > thres);
        v[i] = keep ? x : 0.f;
        if (keep) {
            int slot = atomicAdd(&s_cnt, 1);
            if (slot < SEL_CAP) {
                sel_idx[(size_t)row * SEL_CAP + slot] = i;
                sel_val[(size_t)row * SEL_CAP + slot] = x;
            }
        }
    }
    __syncthreads();
    if (tid == 0) sel_cnt[row] = (s_cnt > SEL_CAP) ? SEL_CAP : s_cnt;
}

// ---------------------------------------------------------------------------
extern "C" void kernel_launch(void* const* d_in, const int* in_sizes, int n_in,
                              void* d_out, int out_size, void* d_ws, size_t ws_size,
                              hipStream_t stream) {
    const float* embv = (const float*)d_in[0];
    const float* embt = (const float*)d_in[1];
    const float* enc  = (const float*)d_in[2];
    const float* Wv   = (const float*)d_in[3];
    const float* bv   = (const float*)d_in[4];
    const float* Wt   = (const float*)d_in[5];
    const float* bt   = (const float*)d_in[6];
    const int* topk   = (const int*)d_in[7];
    float* out = (float*)d_out;

    float* recon_out = out;                              // [2][N][D]
    float* latent = out + (size_t)2 * N_ROWS * D_DIM;    // [2][N][H]

    char* ws = (char*)d_ws;
    size_t off = 0;
    float* invA = (float*)(ws + off);            off += (size_t)M_TOT * 4;
    float* invB = (float*)(ws + off);            off += (size_t)H_DIM * 4;
    int*   sel_cnt = (int*)(ws + off);           off += (size_t)M_TOT * 4;
    int*   amb_cnt = (int*)(ws + off);           off += (size_t)M_TOT * 4;
    int*   sel_idx = (int*)(ws + off);           off += (size_t)M_TOT * SEL_CAP * 4;
    float* sel_val = (float*)(ws + off);         off += (size_t)M_TOT * SEL_CAP * 4;
    int*   amb_idx = (int*)(ws + off);           off += (size_t)M_TOT * AMB_CAP * 4;
    int*   cand_cnt = (int*)(ws + off);          off += (size_t)M_TOT * 4;   // keep cnt+flag adjacent
    int*   flag     = (int*)(ws + off);          off += (size_t)M_TOT * 4;
    unsigned short* Ahi = (unsigned short*)(ws + off); off += (size_t)M_TOT * D_DIM * 2;
    unsigned short* Alo = (unsigned short*)(ws + off); off += (size_t)M_TOT * D_DIM * 2;
    unsigned short* Bh  = (unsigned short*)(ws + off); off += (size_t)H_DIM * D_DIM * 2;
    size_t core_need = off;

    // candidate buffers alias the WvT/WtT region: cand is dead before
    // transpose_kernel runs (readers: cand_select only).
    int*   cand_idx = (int*)(ws + off);
    float* cand_val = (float*)(ws + off + (size_t)M_TOT * CCAP * 4);
    size_t cand_bytes = (size_t)M_TOT * CCAP * 8;             // 33.5 MB
    float* WvT = (float*)(ws + off);
    float* WtT = WvT + (size_t)D_DIM * H_DIM;
    size_t trans_bytes = (size_t)2 * D_DIM * H_DIM * 4;       // 100 MB

    if (ws_size >= core_need + cand_bytes) {
        bool use_T = ws_size >= core_need + trans_bytes;

        split_all_kernel<<<2 * N_ROWS + H_DIM, 256, 0, stream>>>(
            embv, embt, enc, Ahi, Alo, Bh, invA, invB);

        // capture-safe zeroing of latent + cand_cnt/flag (replaces memset)
        zero_fill_kernel<<<2048, 256, 0, stream>>>(
            (floatx4*)latent, (long)((size_t)2 * N_ROWS * H_DIM / 4),
            cand_cnt, 2 * M_TOT);

        gemm_mfma_kernel<<<dim3(H_DIM / 128, M_TOT / 128), 256, 0, stream>>>(
            Ahi, Alo, Bh, cand_cnt, cand_idx, cand_val);

        cand_select_kernel<<<M_TOT, 256, 0, stream>>>(
            cand_cnt, cand_idx, cand_val, latent,
            sel_cnt, sel_idx, sel_val, amb_cnt, amb_idx, flag);

        fallback_kernel<<<M_TOT, 256, 0, stream>>>(
            flag, embv, embt, enc, invA, invB, latent,
            sel_cnt, sel_idx, sel_val, amb_cnt);

        refine_kernel<<<M_TOT, 256, 0, stream>>>(embv, embt, enc, invA, invB,
            latent, sel_cnt, sel_idx, sel_val, amb_cnt, amb_idx);

        if (use_T) {
            transpose_kernel<<<dim3(H_DIM / 32, D_DIM / 32, 2), 256, 0, stream>>>(
                Wv, Wt, WvT, WtT);
            recon_kernel<<<dim3(N_ROWS, 2), 256, 0, stream>>>(
                WvT, WtT, bv, bt, sel_cnt, sel_idx, sel_val, (long)D_DIM, 1L, recon_out);
        } else {
            recon_kernel<<<dim3(N_ROWS, 2), 256, 0, stream>>>(
                Wv, Wt, bv, bt, sel_cnt, sel_idx, sel_val, 1L, (long)H_DIM, recon_out);
        }
    } else {
        // legacy all-fp32 path (small workspace)
        size_t o2 = 0;
        float* inv_enc = (float*)(ws + o2); o2 += (size_t)H_DIM * 4;
        float* inv_emb = (float*)(ws + o2); o2 += (size_t)2 * N_ROWS * 4;
        int*   l_cnt = (int*)(ws + o2);     o2 += (size_t)2 * N_ROWS * 4;
        int*   l_idx = (int*)(ws + o2);     o2 += (size_t)2 * N_ROWS * SEL_CAP * 4;
        float* l_val = (float*)(ws + o2);   o2 += (size_t)2 * N_ROWS * SEL_CAP * 4;
        row_invnorm_kernel<<<H_DIM / 4, 256, 0, stream>>>(enc, inv_enc, H_DIM);
        row_invnorm_kernel<<<N_ROWS / 4, 256, 0, stream>>>(embv, inv_emb, N_ROWS);
        row_invnorm_kernel<<<N_ROWS / 4, 256, 0, stream>>>(embt, inv_emb + N_ROWS, N_ROWS);
        dim3 g(H_DIM / BN, N_ROWS / BM, 2);
        gemm_sim_kernel<<<g, 256, 0, stream>>>(embv, embt, enc, inv_emb, inv_enc, latent);
        legacy_select_kernel<<<2 * N_ROWS, 256, 0, stream>>>(latent, topk, l_cnt, l_idx, l_val);
        recon_kernel<<<dim3(N_ROWS, 2), 256, 0, stream>>>(
            Wv, Wt, bv, bt, l_cnt, l_idx, l_val, 1L, (long)H_DIM, recon_out);
    }
}

// Round 6
// 1453.575 us; speedup vs baseline: 1.3911x; 1.3911x over previous
//
#include <hip/hip_runtime.h>
#include <math.h>

// ============================================================================
// VL_SAE: N=4096, D=768, H=16384, topk=32
// Round 9: fix the Round-8 regression (GEMM 689->1100 us).
//   Diagnosis: epilogue did 64 per-lane global atomicAdd-with-return ops per
//   thread (divergent, serialized ~600cy each) => ~400 us atomic-latency tail
//   (MfmaUtil 26->15.6 with unchanged MFMA cycles proves main loop unchanged).
//   Fix: LDS-staged candidate lists (LDS atomics, reuse sA after a barrier),
//   then ONE global atomicAdd per (block,row) by 128 flush threads + short
//   coalesced writes. Per-block-row cap SCAP=24 (P(overflow)~1e-13); overflow
//   adds CCAP+1 to the row counter -> deterministic exact-fallback flag.
//   Also: -2 dispatches. cand_select zeroes its own latent row (zero_fill
//   gone); fallback+refine merged into finalize_kernel (flag XOR amb per row);
//   cand_cnt/flag zeroing folded into split_all's first 64 blocks.
// Round 6-8 (kept): candidate-list algorithm. sim=2-sqrt(2-2cos) monotone in
//   cos => top-k by cos; GEMM appends cos>=THR_COS (~220/row); per-row
//   deterministic certification (cnt in [33,CCAP], v*-MARGIN > guard) else
//   exact dense fallback. Removes the 1.5 GB dense latent round trip.
// Round 4 (kept): GEMM core = 48KB dbuf, vmcnt(6), 2 barriers/K-step,
//   bounds(256,3), setprio, XCD swizzle. Round 3 (kept): split bf16 GEMM,
//   MARGIN classify + exact refine.
// ============================================================================

#define N_ROWS 4096
#define D_DIM  768
#define H_DIM  16384
#define M_TOT  8192
#define TOPK   32
#define MARGIN 1e-3f
#define SEL_CAP 40
#define AMB_CAP 64
#define CCAP   512
#define SCAP   24      // per (row, 128-col block) candidate cap
// cos filter: ~2.2 sigma (sigma = 1/sqrt(768) = 0.036). Row 33rd-largest
// cos ~ 0.104 (2.9 sigma). sim(0.08) = 2 - sqrt(1.84) = 0.643534.
#define THR_COS 0.08f
#define THR_SIM_GUARD 0.6436f

typedef __attribute__((ext_vector_type(8))) short short8;
typedef __attribute__((ext_vector_type(4))) float floatx4;

__device__ inline unsigned short bf16_rne(float f) {
    unsigned u = __float_as_uint(f);
    unsigned r = u + 0x7fffu + ((u >> 16) & 1u);
    return (unsigned short)(r >> 16);
}

__device__ inline void gload16(const unsigned short* g, unsigned short* l) {
    __builtin_amdgcn_global_load_lds(
        (const __attribute__((address_space(1))) void*)g,
        (__attribute__((address_space(3))) void*)l, 16, 0, 0);
}

// ---------------------------------------------------------------------------
// normalize rows of embv/embt/enc; emb -> bf16 hi+lo, enc -> bf16 hi only.
// First 64 blocks also zero cand_cnt+flag (2*M_TOT adjacent ints).
__global__ void split_all_kernel(const float* __restrict__ embv,
                                 const float* __restrict__ embt,
                                 const float* __restrict__ enc,
                                 unsigned short* __restrict__ Ahi,
                                 unsigned short* __restrict__ Alo,
                                 unsigned short* __restrict__ Bh,
                                 float* __restrict__ invA,
                                 float* __restrict__ invB,
                                 int* __restrict__ cntflag)
{
    int row = blockIdx.x;                  // 0..2N+H-1
    int tid = threadIdx.x;
    if (row < 64) {                        // 64*256 == 2*M_TOT exactly
        cntflag[row * 256 + tid] = 0;
    }
    const float* src;
    unsigned short *hi, *lo;
    float* invp;
    if (row < N_ROWS) {
        src = embv + (size_t)row * D_DIM;
        hi = Ahi + (size_t)row * D_DIM; lo = Alo + (size_t)row * D_DIM;
        invp = invA + row;
    } else if (row < 2 * N_ROWS) {
        int r = row - N_ROWS;
        src = embt + (size_t)r * D_DIM;
        hi = Ahi + (size_t)row * D_DIM; lo = Alo + (size_t)row * D_DIM;
        invp = invA + row;
    } else {
        int r = row - 2 * N_ROWS;
        src = enc + (size_t)r * D_DIM;
        hi = Bh + (size_t)r * D_DIM; lo = nullptr;
        invp = invB + r;
    }
    __shared__ float red[4];
    const float4* s4 = reinterpret_cast<const float4*>(src);
    float4 v = make_float4(0.f, 0.f, 0.f, 0.f);
    float ss = 0.f;
    if (tid < 192) {
        v = s4[tid];
        ss = v.x * v.x + v.y * v.y + v.z * v.z + v.w * v.w;
    }
    #pragma unroll
    for (int o = 32; o > 0; o >>= 1) ss += __shfl_down(ss, o);
    int wave = tid >> 6, lane = tid & 63;
    if (lane == 0) red[wave] = ss;
    __syncthreads();
    if (tid == 0) {
        float tot = red[0] + red[1] + red[2];
        red[0] = 1.f / fmaxf(sqrtf(tot), 1e-12f);
    }
    __syncthreads();
    float inv = red[0];
    if (tid == 0) *invp = inv;
    if (tid < 192) {
        float x[4] = {v.x * inv, v.y * inv, v.z * inv, v.w * inv};
        unsigned short hh[4], ll[4];
        #pragma unroll
        for (int t = 0; t < 4; t++) {
            hh[t] = bf16_rne(x[t]);
            float hf = __uint_as_float((unsigned)hh[t] << 16);
            ll[t] = bf16_rne(x[t] - hf);
        }
        ushort4 h4; h4.x = hh[0]; h4.y = hh[1]; h4.z = hh[2]; h4.w = hh[3];
        *reinterpret_cast<ushort4*>(hi + tid * 4) = h4;
        if (lo) {
            ushort4 l4; l4.x = ll[0]; l4.y = ll[1]; l4.z = ll[2]; l4.w = ll[3];
            *reinterpret_cast<ushort4*>(lo + tid * 4) = l4;
        }
    }
}

// ---------------------------------------------------------------------------
// 2-product split GEMM: cos = (Ahi+Alo) . Bh  (inputs pre-normalized)
// Round-4 pipeline core; Round-9 epilogue: LDS-staged candidate flush.
#define GBK 32
#define NTILE (D_DIM / GBK)   // 24

__global__ __launch_bounds__(256, 3)
void gemm_mfma_kernel(const unsigned short* __restrict__ Ahi,
                      const unsigned short* __restrict__ Alo,
                      const unsigned short* __restrict__ Bh,
                      int* __restrict__ cand_cnt,
                      int* __restrict__ cand_idx,
                      float* __restrict__ cand_val)
{
    __shared__ unsigned short sA[2][2][128 * GBK];
    __shared__ unsigned short sB[2][128 * GBK];

    int tid = threadIdx.x;
    int lane = tid & 63;
    int wave = tid >> 6;
    int wr = (wave >> 1) * 64;
    int wc = (wave & 1) * 64;
    int m = lane & 15;
    int q = lane >> 4;

    // XCD-aware bijective swizzle: grid = 128x64 = 8192 blocks, 8192 % 8 == 0.
    unsigned nwgx = gridDim.x;                        // 128
    unsigned lid = blockIdx.y * nwgx + blockIdx.x;
    unsigned cpx = (nwgx * gridDim.y) >> 3;           // 1024
    unsigned swz = (lid & 7u) * cpx + (lid >> 3);
    int bx = (int)(swz % nwgx);
    int by = (int)(swz / nwgx);

    int row0 = by * 128;
    int col0 = bx * 128;

    int p0 = tid, p1 = tid + 256;
    int r0 = ((p0 >> 5) << 3) | (p0 & 7), q0 = (p0 >> 3) & 3;
    int r1 = ((p1 >> 5) << 3) | (p1 & 7), q1 = (p1 >> 3) & 3;
    size_t aoff0 = (size_t)(row0 + r0) * D_DIM + q0 * 8;
    size_t aoff1 = (size_t)(row0 + r1) * D_DIM + q1 * 8;
    size_t boff0 = (size_t)(col0 + r0) * D_DIM + q0 * 8;
    size_t boff1 = (size_t)(col0 + r1) * D_DIM + q1 * 8;

    int am0 = wr + m;
    int bn0 = wc + m;
    int offA = ((am0 >> 3) << 8) + (q << 6) + ((am0 & 7) << 3);
    int offB = ((bn0 >> 3) << 8) + (q << 6) + ((bn0 & 7) << 3);

    floatx4 acc[4][4];
    #pragma unroll
    for (int i = 0; i < 4; i++)
        #pragma unroll
        for (int j = 0; j < 4; j++)
            acc[i][j] = (floatx4){0.f, 0.f, 0.f, 0.f};

    // 6 global_load_lds per stage (vmcnt unit)
    auto stage = [&](int t, int b) {
        int k0 = t * GBK;
        gload16(Ahi + aoff0 + k0, &sA[b][0][p0 * 8]);
        gload16(Ahi + aoff1 + k0, &sA[b][0][p1 * 8]);
        gload16(Alo + aoff0 + k0, &sA[b][1][p0 * 8]);
        gload16(Alo + aoff1 + k0, &sA[b][1][p1 * 8]);
        gload16(Bh + boff0 + k0, &sB[b][p0 * 8]);
        gload16(Bh + boff1 + k0, &sB[b][p1 * 8]);
    };

    auto compute = [&](int b) {
        short8 fah[4], fal[4], fbv[4];
        #pragma unroll
        for (int i = 0; i < 4; i++) {
            fah[i] = *(const short8*)&sA[b][0][offA + i * 512];
            fal[i] = *(const short8*)&sA[b][1][offA + i * 512];
        }
        #pragma unroll
        for (int j = 0; j < 4; j++)
            fbv[j] = *(const short8*)&sB[b][offB + j * 512];
        __builtin_amdgcn_s_setprio(1);
        #pragma unroll
        for (int j = 0; j < 4; j++) {
            #pragma unroll
            for (int i = 0; i < 4; i++) {
                acc[i][j] = __builtin_amdgcn_mfma_f32_16x16x32_bf16(fah[i], fbv[j], acc[i][j], 0, 0, 0);
                acc[i][j] = __builtin_amdgcn_mfma_f32_16x16x32_bf16(fal[i], fbv[j], acc[i][j], 0, 0, 0);
            }
        }
        __builtin_amdgcn_s_setprio(0);
    };

    // Round-4 pipeline: depth-1 dbuf, vmcnt(6) (tile t retires, t+1 stays in
    // flight), 2 barriers/K-step. Measured best (641 us vs 689 for 3-buf).
    stage(0, 0);
    int cur = 0;
    for (int t = 0; t < NTILE - 1; ++t) {
        stage(t + 1, cur ^ 1);
        asm volatile("s_waitcnt vmcnt(6)" ::: "memory");
        __builtin_amdgcn_s_barrier();
        __builtin_amdgcn_sched_barrier(0);
        compute(cur);
        __builtin_amdgcn_sched_barrier(0);
        __builtin_amdgcn_s_barrier();
        cur ^= 1;
    }
    asm volatile("s_waitcnt vmcnt(0)" ::: "memory");
    __builtin_amdgcn_s_barrier();
    __builtin_amdgcn_sched_barrier(0);
    compute(cur);

    // ---- Epilogue: LDS-staged candidate flush (fixes round-8 atomic tail) --
    // Stage candidates into per-row LDS lists (LDS atomics), then 128 threads
    // flush with ONE global atomicAdd per (block,row) + short coalesced writes.
    __syncthreads();                        // all waves done reading sA
    int*   s_rcnt = (int*)(&sA[0][0][0]);   // 128 ints
    int*   s_ridx = s_rcnt + 128;           // 128*SCAP ints
    float* s_rval = (float*)(s_ridx + 128 * SCAP);   // 128*SCAP floats (25KB tot)
    if (tid < 128) s_rcnt[tid] = 0;
    __syncthreads();

    #pragma unroll
    for (int i = 0; i < 4; i++) {
        #pragma unroll
        for (int r = 0; r < 4; r++) {
            int lrow = wr + i * 16 + q * 4 + r;          // 0..127
            #pragma unroll
            for (int j = 0; j < 4; j++) {
                float cosv = acc[i][j][r];
                if (cosv >= THR_COS) {
                    int s = atomicAdd(&s_rcnt[lrow], 1);  // LDS atomic, cheap
                    if (s < SCAP) {
                        s_ridx[lrow * SCAP + s] = wc + m + j * 16;  // 0..127
                        s_rval[lrow * SCAP + s] = cosv;
                    }
                }
            }
        }
    }
    __syncthreads();

    if (tid < 128) {
        int c = s_rcnt[tid];
        if (c > 0) {
            int grow = row0 + tid;
            int wcnt = (c > SCAP) ? SCAP : c;
            // overflow (impossible statistically) forces cnt > CCAP -> exact path
            int addc = (c > SCAP) ? (CCAP + 1) : c;
            int base = atomicAdd(&cand_cnt[grow], addc);  // 1 atomic per (blk,row)
            for (int s2 = 0; s2 < wcnt; ++s2) {
                int slot = base + s2;
                if (slot < CCAP) {
                    cand_idx[(size_t)grow * CCAP + slot] = col0 + s_ridx[tid * SCAP + s2];
                    cand_val[(size_t)grow * CCAP + slot] = s_rval[tid * SCAP + s2];
                }
            }
        }
    }
}

// ---------------------------------------------------------------------------
// Per-row: zero own latent row, then select over the candidate list
// (~220 entries). Same proven MARGIN classify; flags row for exact fallback
// if the static filter cannot be certified for this row.
__global__ __launch_bounds__(256)
void cand_select_kernel(const int* __restrict__ cand_cnt,
                        const int* __restrict__ cand_idx,
                        const float* __restrict__ cand_val,
                        float* __restrict__ latent,
                        int* __restrict__ sel_cnt,
                        int* __restrict__ sel_idx,
                        float* __restrict__ sel_val,
                        int* __restrict__ amb_cnt,
                        int* __restrict__ amb_idx,
                        int* __restrict__ flag)
{
    int row = blockIdx.x;
    int tid = threadIdx.x;
    float* v = latent + (size_t)row * H_DIM;

    // zero own latent row (mandatory output bytes; replaces zero_fill kernel)
    floatx4* vw = (floatx4*)v;
    floatx4 z = (floatx4){0.f, 0.f, 0.f, 0.f};
    #pragma unroll
    for (int k = 0; k < 16; k++)
        __builtin_nontemporal_store(z, &vw[tid + 256 * k]);

    int cnt = cand_cnt[row];

    __shared__ float sv[CCAP];
    __shared__ int   si[CCAP];
    __shared__ int svstar, skept, samb;

    if (cnt > CCAP || cnt < TOPK + 1) {          // overflow or too few: exact path
        if (tid == 0) { flag[row] = 1; sel_cnt[row] = 0; amb_cnt[row] = 0; }
        return;
    }
    for (int c = tid; c < cnt; c += 256) {
        float cosv = cand_val[(size_t)row * CCAP + c];
        sv[c] = 2.f - sqrtf(fmaxf(2.f - 2.f * cosv, 0.f));   // same fp32 ops
        si[c] = cand_idx[(size_t)row * CCAP + c];
    }
    if (tid == 0) { svstar = 0x7FFFFFFF; skept = 0; samb = 0; }
    __syncthreads();

    // v* = 33rd largest candidate sim (== 33rd largest overall, since every
    // candidate >= every non-candidate and cnt >= 33). Slot-order tie-break;
    // boundary ties land in the ambiguous band and are refined exactly.
    for (int c = tid; c < cnt; c += 256) {
        float a = sv[c];
        int g = 0;
        for (int j = 0; j < cnt; j++) {
            float aj = sv[j];
            g += (aj > a || (aj == a && j < c)) ? 1 : 0;
        }
        if (g <= TOPK) atomicMin(&svstar, __float_as_int(a));
    }
    __syncthreads();
    float vs = __int_as_float(svstar);

    // Certify the static filter: every non-candidate has approx sim <
    // THR_SIM_GUARD < vs - MARGIN  =>  certain drop under the round-3 rule.
    if (vs - MARGIN <= THR_SIM_GUARD) {
        if (tid == 0) { flag[row] = 1; sel_cnt[row] = 0; amb_cnt[row] = 0; }
        return;
    }

    // classify (scatter after __syncthreads: zero-stores already drained by
    // the compiler's vmcnt(0)-before-barrier, so ordering is safe)
    for (int c = tid; c < cnt; c += 256) {
        float f = sv[c];
        int idx = si[c];
        if (f > vs + MARGIN) {
            int s = atomicAdd(&skept, 1);
            sel_idx[(size_t)row * SEL_CAP + s] = idx;
            sel_val[(size_t)row * SEL_CAP + s] = f;
            v[idx] = f;
        } else if (f >= vs - MARGIN) {
            int s = atomicAdd(&samb, 1);
            if (s < AMB_CAP) amb_idx[(size_t)row * AMB_CAP + s] = idx;
        }
    }
    __syncthreads();
    if (tid == 0) { sel_cnt[row] = skept; amb_cnt[row] = min(samb, AMB_CAP); }
}

// ---------------------------------------------------------------------------
// finalize = fallback | refine (mutually exclusive per row).
// Flagged rows: exact fp32 dense recompute into the latent row (global,
// already zeroed) + radix-exact top-(k+1) threshold + strictly-greater keep.
// Ambiguous rows: exact fp32 recompute of amb entries, tie-aware top-off.
__global__ __launch_bounds__(256)
void finalize_kernel(const int* __restrict__ flag,
                     const float* __restrict__ embv,
                     const float* __restrict__ embt,
                     const float* __restrict__ enc,
                     const float* __restrict__ invA,
                     const float* __restrict__ invB,
                     float* __restrict__ latent,
                     int* __restrict__ sel_cnt,
                     int* __restrict__ sel_idx,
                     float* __restrict__ sel_val,
                     int* __restrict__ amb_cnt,
                     const int* __restrict__ amb_idx)
{
    int row = blockIdx.x;
    int tid = threadIdx.x;
    float* v = latent + (size_t)row * H_DIM;
    const float* src = (row < N_ROWS) ? embv + (size_t)row * D_DIM
                                      : embt + (size_t)(row - N_ROWS) * D_DIM;
    float ia = invA[row];

    __shared__ float ssrc[D_DIM];
    __shared__ unsigned hist[256];
    __shared__ unsigned s_prefix;
    __shared__ int s_k, s_cnt;
    __shared__ float ex[AMB_CAP];
    __shared__ int evs, kc;

    if (flag[row]) {
        // ---------------- exact dense fallback ----------------
        for (int d = tid; d < D_DIM; d += 256) ssrc[d] = src[d];
        __syncthreads();
        for (int h = tid; h < H_DIM; h += 256) {
            const float* w = enc + (size_t)h * D_DIM;
            float d = 0.f;
            for (int t = 0; t < D_DIM; t++) d += ssrc[t] * w[t];
            float cosv = d * ia * invB[h];
            v[h] = 2.f - sqrtf(fmaxf(2.f - 2.f * cosv, 0.f));
        }
        __syncthreads();
        // radix-select the 33rd largest (sims >= 0 -> raw bits monotone)
        int k = TOPK + 1;
        unsigned prefix = 0;
        for (int shift = 24; shift >= 0; shift -= 8) {
            hist[tid] = 0;
            __syncthreads();
            unsigned pmask = (shift == 24) ? 0u : (0xFFFFFFFFu << (shift + 8));
            for (int i = tid; i < H_DIM; i += 256) {
                unsigned u = __float_as_uint(v[i]);
                if ((u & pmask) == prefix)
                    atomicAdd(&hist[(u >> shift) & 255u], 1u);
            }
            __syncthreads();
            if (tid == 0) {
                int c = 0, b = 255;
                for (; b >= 0; b--) {
                    c += (int)hist[b];
                    if (c >= k) break;
                }
                if (b < 0) b = 0;
                s_prefix = prefix | ((unsigned)b << shift);
                s_k = k - (c - (int)hist[b]);
            }
            __syncthreads();
            prefix = s_prefix;
            k = s_k;
            __syncthreads();
        }
        float thres = __uint_as_float(prefix);
        if (tid == 0) s_cnt = 0;
        __syncthreads();
        for (int i = tid; i < H_DIM; i += 256) {
            float x = v[i];
            bool keep = (x > thres);
            v[i] = keep ? x : 0.f;
            if (keep) {
                int slot = atomicAdd(&s_cnt, 1);
                if (slot < SEL_CAP) {
                    sel_idx[(size_t)row * SEL_CAP + slot] = i;
                    sel_val[(size_t)row * SEL_CAP + slot] = x;
                }
            }
        }
        __syncthreads();
        if (tid == 0) {
            sel_cnt[row] = (s_cnt > SEL_CAP) ? SEL_CAP : s_cnt;
            amb_cnt[row] = 0;
        }
        return;
    }

    // ---------------- refine (ambiguous entries) ----------------
    int s = amb_cnt[row];
    if (s == 0) return;
    int m = sel_cnt[row];
    int need = TOPK - m;
    if (need <= 0) return;                 // ambiguous slots already zero
    int wave = tid >> 6, lane = tid & 63;
    for (int a = wave; a < s; a += 4) {
        int h = amb_idx[(size_t)row * AMB_CAP + a];
        const float* w = enc + (size_t)h * D_DIM;
        float d = 0.f;
        for (int t = lane; t < D_DIM; t += 64) d += src[t] * w[t];
        #pragma unroll
        for (int o = 32; o > 0; o >>= 1) d += __shfl_down(d, o);
        if (lane == 0) {
            float cosv = d * ia * invB[h];
            ex[a] = 2.f - sqrtf(fmaxf(2.f - 2.f * cosv, 0.f));
        }
    }
    if (tid == 0) { evs = 0x7FFFFFFF; kc = 0; }
    __syncthreads();
    if (tid < s) {
        float mya = fabsf(ex[tid]);
        int g = 0;
        for (int j = 0; j < s; j++) {
            float aj = fabsf(ex[j]);
            g += (aj > mya || (aj == mya && j < tid)) ? 1 : 0;
        }
        if (g <= need) atomicMin(&evs, __float_as_int(mya));
    }
    __syncthreads();
    float ep = __int_as_float(evs);
    if (tid < s) {
        int idx = amb_idx[(size_t)row * AMB_CAP + tid];
        float e = ex[tid];
        if (fabsf(e) > ep) {
            int sl = atomicAdd(&kc, 1);
            v[idx] = e;
            sel_idx[(size_t)row * SEL_CAP + m + sl] = idx;
            sel_val[(size_t)row * SEL_CAP + m + sl] = e;
        }
    }
    __syncthreads();
    if (tid == 0) sel_cnt[row] = m + kc;
}

// ---------------------------------------------------------------------------
__global__ void transpose_kernel(const float* __restrict__ Wv,
                                 const float* __restrict__ Wt,
                                 float* __restrict__ WvT,
                                 float* __restrict__ WtT)
{
    int z = blockIdx.z;
    const float* W = z ? Wt : Wv;
    float* WT = z ? WtT : WvT;
    __shared__ float tile[32][33];
    int tx = threadIdx.x & 31;
    int ty = threadIdx.x >> 5;
    int h0 = blockIdx.x * 32;
    int d0 = blockIdx.y * 32;
    #pragma unroll
    for (int t = 0; t < 4; t++)
        tile[ty + t * 8][tx] = W[(size_t)(d0 + ty + t * 8) * H_DIM + h0 + tx];
    __syncthreads();
    #pragma unroll
    for (int t = 0; t < 4; t++)
        WT[(size_t)(h0 + ty + t * 8) * D_DIM + d0 + tx] = tile[tx][ty + t * 8];
}

// ---------------------------------------------------------------------------
__global__ void recon_kernel(const float* __restrict__ Wv_,
                             const float* __restrict__ Wt_,
                             const float* __restrict__ bv,
                             const float* __restrict__ bt,
                             const int* __restrict__ sel_cnt,
                             const int* __restrict__ sel_idx,
                             const float* __restrict__ sel_val,
                             long sh, long sd,
                             float* __restrict__ out)
{
    int n = blockIdx.x;
    int z = blockIdx.y;
    int row = z * N_ROWS + n;
    const float* W = z ? Wt_ : Wv_;
    const float* bias = z ? bt : bv;
    float* o = out + (size_t)z * N_ROWS * D_DIM + (size_t)n * D_DIM;

    __shared__ int s_idx[SEL_CAP];
    __shared__ float s_val[SEL_CAP];
    __shared__ int s_cnt;
    int tid = threadIdx.x;
    if (tid == 0) s_cnt = sel_cnt[row];
    __syncthreads();
    int cnt = s_cnt;
    if (tid < cnt) {
        s_idx[tid] = sel_idx[(size_t)row * SEL_CAP + tid];
        s_val[tid] = sel_val[(size_t)row * SEL_CAP + tid];
    }
    __syncthreads();

    for (int d = tid; d < D_DIM; d += 256) {
        float acc = bias[d];
        for (int j = 0; j < cnt; j++)
            acc += s_val[j] * W[(size_t)s_idx[j] * sh + (size_t)d * sd];
        o[d] = acc;
    }
}

// ============================ LEGACY FALLBACK ==============================
__global__ void row_invnorm_kernel(const float* __restrict__ x,
                                   float* __restrict__ inv, int rows) {
    int row = blockIdx.x * 4 + (threadIdx.x >> 6);
    int lane = threadIdx.x & 63;
    if (row >= rows) return;
    const float4* p = reinterpret_cast<const float4*>(x + (size_t)row * D_DIM);
    float ss = 0.f;
    #pragma unroll
    for (int i = 0; i < 3; i++) {
        float4 v = p[lane + i * 64];
        ss += v.x * v.x + v.y * v.y + v.z * v.z + v.w * v.w;
    }
    #pragma unroll
    for (int off = 32; off > 0; off >>= 1) ss += __shfl_down(ss, off);
    if (lane == 0) inv[row] = 1.f / fmaxf(sqrtf(ss), 1e-12f);
}

#define BM 128
#define BN 128
#define BK 16
__global__ __launch_bounds__(256)
void gemm_sim_kernel(const float* __restrict__ embv,
                     const float* __restrict__ embt,
                     const float* __restrict__ enc,
                     const float* __restrict__ inv_emb,
                     const float* __restrict__ inv_enc,
                     float* __restrict__ latent)
{
    int z = blockIdx.z;
    const float* A = z ? embt : embv;
    const float* invA = inv_emb + z * N_ROWS;
    float* C = latent + (size_t)z * N_ROWS * H_DIM;
    __shared__ float As[BK][BM + 4];
    __shared__ float Bs[BK][BN + 4];
    int tid = threadIdx.x;
    int tx = tid & 15, ty = tid >> 4;
    int row0 = blockIdx.y * BM, col0 = blockIdx.x * BN;
    float acc[8][8];
    #pragma unroll
    for (int i = 0; i < 8; i++)
        #pragma unroll
        for (int j = 0; j < 8; j++) acc[i][j] = 0.f;
    for (int k0 = 0; k0 < D_DIM; k0 += BK) {
        #pragma unroll
        for (int t = 0; t < 2; t++) {
            int idx = t * 256 + tid;
            int r = idx >> 2, c4 = idx & 3;
            float4 va = *reinterpret_cast<const float4*>(
                A + (size_t)(row0 + r) * D_DIM + k0 + c4 * 4);
            As[c4 * 4 + 0][r] = va.x; As[c4 * 4 + 1][r] = va.y;
            As[c4 * 4 + 2][r] = va.z; As[c4 * 4 + 3][r] = va.w;
            float4 vb = *reinterpret_cast<const float4*>(
                enc + (size_t)(col0 + r) * D_DIM + k0 + c4 * 4);
            Bs[c4 * 4 + 0][r] = vb.x; Bs[c4 * 4 + 1][r] = vb.y;
            Bs[c4 * 4 + 2][r] = vb.z; Bs[c4 * 4 + 3][r] = vb.w;
        }
        __syncthreads();
        #pragma unroll
        for (int kk = 0; kk < BK; kk++) {
            float a[8], b[8];
            *reinterpret_cast<float4*>(&a[0]) = *reinterpret_cast<const float4*>(&As[kk][ty * 8]);
            *reinterpret_cast<float4*>(&a[4]) = *reinterpret_cast<const float4*>(&As[kk][ty * 8 + 4]);
            *reinterpret_cast<float4*>(&b[0]) = *reinterpret_cast<const float4*>(&Bs[kk][tx * 8]);
            *reinterpret_cast<float4*>(&b[4]) = *reinterpret_cast<const float4*>(&Bs[kk][tx * 8 + 4]);
            #pragma unroll
            for (int i = 0; i < 8; i++)
                #pragma unroll
                for (int j = 0; j < 8; j++)
                    acc[i][j] = fmaf(a[i], b[j], acc[i][j]);
        }
        __syncthreads();
    }
    #pragma unroll
    for (int i = 0; i < 8; i++) {
        int n = row0 + ty * 8 + i;
        float sa = invA[n];
        float* Crow = C + (size_t)n * H_DIM + col0 + tx * 8;
        float tmp[8];
        #pragma unroll
        for (int j = 0; j < 8; j++) {
            float cosv = acc[i][j] * sa * inv_enc[col0 + tx * 8 + j];
            tmp[j] = 2.f - sqrtf(fmaxf(2.f - 2.f * cosv, 0.f));
        }
        float4 o0 = {tmp[0], tmp[1], tmp[2], tmp[3]};
        float4 o1 = {tmp[4], tmp[5], tmp[6], tmp[7]};
        *reinterpret_cast<float4*>(Crow) = o0;
        *reinterpret_cast<float4*>(Crow + 4) = o1;
    }
}

__global__ void legacy_select_kernel(float* __restrict__ latent,
                                     const int* __restrict__ topk_p,
                                     int* __restrict__ sel_cnt,
                                     int* __restrict__ sel_idx,
                                     float* __restrict__ sel_val)
{
    int row = blockIdx.x;
    float* v = latent + (size_t)row * H_DIM;
    int tid = threadIdx.x;
    __shared__ unsigned hist[256];
    __shared__ unsigned s_prefix;
    __shared__ int s_k;
    __shared__ int s_cnt;
    int k = topk_p[0] + 1;
    unsigned prefix = 0;
    for (int shift = 24; shift >= 0; shift -= 8) {
        hist[tid] = 0;
        __syncthreads();
        unsigned pmask = (shift == 24) ? 0u : (0xFFFFFFFFu << (shift + 8));
        for (int i = tid; i < H_DIM; i += 256) {
            unsigned u = __float_as_uint(v[i]) & 0x7FFFFFFFu;
            if ((u & pmask) == prefix)
                atomicAdd(&hist[(u >> shift) & 255u], 1u);
        }
        __syncthreads();
        if (tid == 0) {
            int c = 0, b = 255;
            for (; b >= 0; b--) {
                c += (int)hist[b];
                if (c >= k) break;
            }
            if (b < 0) b = 0;
            s_prefix = prefix | ((unsigned)b << shift);
            s_k = k - (c - (int)hist[b]);
        }
        __syncthreads();
        prefix = s_prefix;
        k = s_k;
        __syncthreads();
    }
    float thres = __uint_as_float(prefix);
    if (tid == 0) s_cnt = 0;
    __syncthreads();
    for (int i = tid; i < H_DIM; i += 256) {
        float x = v[i];
        bool keep = (fabsf(x) > thres);
        v[i] = keep ? x : 0.f;
        if (keep) {
            int slot = atomicAdd(&s_cnt, 1);
            if (slot < SEL_CAP) {
                sel_idx[(size_t)row * SEL_CAP + slot] = i;
                sel_val[(size_t)row * SEL_CAP + slot] = x;
            }
        }
    }
    __syncthreads();
    if (tid == 0) sel_cnt[row] = (s_cnt > SEL_CAP) ? SEL_CAP : s_cnt;
}

// ---------------------------------------------------------------------------
extern "C" void kernel_launch(void* const* d_in, const int* in_sizes, int n_in,
                              void* d_out, int out_size, void* d_ws, size_t ws_size,
                              hipStream_t stream) {
    const float* embv = (const float*)d_in[0];
    const float* embt = (const float*)d_in[1];
    const float* enc  = (const float*)d_in[2];
    const float* Wv   = (const float*)d_in[3];
    const float* bv   = (const float*)d_in[4];
    const float* Wt   = (const float*)d_in[5];
    const float* bt   = (const float*)d_in[6];
    const int* topk   = (const int*)d_in[7];
    float* out = (float*)d_out;

    float* recon_out = out;                              // [2][N][D]
    float* latent = out + (size_t)2 * N_ROWS * D_DIM;    // [2][N][H]

    char* ws = (char*)d_ws;
    size_t off = 0;
    float* invA = (float*)(ws + off);            off += (size_t)M_TOT * 4;
    float* invB = (float*)(ws + off);            off += (size_t)H_DIM * 4;
    int*   sel_cnt = (int*)(ws + off);           off += (size_t)M_TOT * 4;
    int*   amb_cnt = (int*)(ws + off);           off += (size_t)M_TOT * 4;
    int*   sel_idx = (int*)(ws + off);           off += (size_t)M_TOT * SEL_CAP * 4;
    float* sel_val = (float*)(ws + off);         off += (size_t)M_TOT * SEL_CAP * 4;
    int*   amb_idx = (int*)(ws + off);           off += (size_t)M_TOT * AMB_CAP * 4;
    int*   cand_cnt = (int*)(ws + off);          off += (size_t)M_TOT * 4;   // cnt+flag adjacent
    int*   flag     = (int*)(ws + off);          off += (size_t)M_TOT * 4;
    unsigned short* Ahi = (unsigned short*)(ws + off); off += (size_t)M_TOT * D_DIM * 2;
    unsigned short* Alo = (unsigned short*)(ws + off); off += (size_t)M_TOT * D_DIM * 2;
    unsigned short* Bh  = (unsigned short*)(ws + off); off += (size_t)H_DIM * D_DIM * 2;
    size_t core_need = off;

    // candidate buffers alias the WvT/WtT region: cand is dead before
    // transpose_kernel runs (readers: cand_select only).
    int*   cand_idx = (int*)(ws + off);
    float* cand_val = (float*)(ws + off + (size_t)M_TOT * CCAP * 4);
    size_t cand_bytes = (size_t)M_TOT * CCAP * 8;             // 33.5 MB
    float* WvT = (float*)(ws + off);
    float* WtT = WvT + (size_t)D_DIM * H_DIM;
    size_t trans_bytes = (size_t)2 * D_DIM * H_DIM * 4;       // 100 MB

    if (ws_size >= core_need + cand_bytes) {
        bool use_T = ws_size >= core_need + trans_bytes;

        split_all_kernel<<<2 * N_ROWS + H_DIM, 256, 0, stream>>>(
            embv, embt, enc, Ahi, Alo, Bh, invA, invB, cand_cnt);

        gemm_mfma_kernel<<<dim3(H_DIM / 128, M_TOT / 128), 256, 0, stream>>>(
            Ahi, Alo, Bh, cand_cnt, cand_idx, cand_val);

        cand_select_kernel<<<M_TOT, 256, 0, stream>>>(
            cand_cnt, cand_idx, cand_val, latent,
            sel_cnt, sel_idx, sel_val, amb_cnt, amb_idx, flag);

        finalize_kernel<<<M_TOT, 256, 0, stream>>>(
            flag, embv, embt, enc, invA, invB, latent,
            sel_cnt, sel_idx, sel_val, amb_cnt, amb_idx);

        if (use_T) {
            transpose_kernel<<<dim3(H_DIM / 32, D_DIM / 32, 2), 256, 0, stream>>>(
                Wv, Wt, WvT, WtT);
            recon_kernel<<<dim3(N_ROWS, 2), 256, 0, stream>>>(
                WvT, WtT, bv, bt, sel_cnt, sel_idx, sel_val, (long)D_DIM, 1L, recon_out);
        } else {
            recon_kernel<<<dim3(N_ROWS, 2), 256, 0, stream>>>(
                Wv, Wt, bv, bt, sel_cnt, sel_idx, sel_val, 1L, (long)H_DIM, recon_out);
        }
    } else {
        // legacy all-fp32 path (small workspace)
        size_t o2 = 0;
        float* inv_enc = (float*)(ws + o2); o2 += (size_t)H_DIM * 4;
        float* inv_emb = (float*)(ws + o2); o2 += (size_t)2 * N_ROWS * 4;
        int*   l_cnt = (int*)(ws + o2);     o2 += (size_t)2 * N_ROWS * 4;
        int*   l_idx = (int*)(ws + o2);     o2 += (size_t)2 * N_ROWS * SEL_CAP * 4;
        float* l_val = (float*)(ws + o2);   o2 += (size_t)2 * N_ROWS * SEL_CAP * 4;
        row_invnorm_kernel<<<H_DIM / 4, 256, 0, stream>>>(enc, inv_enc, H_DIM);
        row_invnorm_kernel<<<N_ROWS / 4, 256, 0, stream>>>(embv, inv_emb, N_ROWS);
        row_invnorm_kernel<<<N_ROWS / 4, 256, 0, stream>>>(embt, inv_emb + N_ROWS, N_ROWS);
        dim3 g(H_DIM / BN, N_ROWS / BM, 2);
        gemm_sim_kernel<<<g, 256, 0, stream>>>(embv, embt, enc, inv_emb, inv_enc, latent);
        legacy_select_kernel<<<2 * N_ROWS, 256, 0, stream>>>(latent, topk, l_cnt, l_idx, l_val);
        recon_kernel<<<dim3(N_ROWS, 2), 256, 0, stream>>>(
            Wv, Wt, bv, bt, l_cnt, l_idx, l_val, 1L, (long)H_DIM, recon_out);
    }
}

// Round 9
// 1419.764 us; speedup vs baseline: 1.4243x; 1.0238x over previous
//
#include <hip/hip_runtime.h>
#include <math.h>

// ============================================================================
// VL_SAE: N=4096, D=768, H=16384, topk=32
// Round 12: resubmission of Round 10/11 (comment-only delta). Both failures
//   lacked even stage_upload_s in timing => broker acquire failed BEFORE the
//   source was staged/compiled; kernel content cannot participate. Third
//   attempt; if it fails again, next round bisects from the known-good R9.
// Round 10: shrink the invisible non-GEMM 845 us. GEMM untouched (608 us).
//   - FUSE cand_select + finalize into select_finalize_kernel: zero row,
//     select, classify, inline refine (amb in LDS) or inline exact dense
//     fallback. -1 dispatch, -1 global round trip. All branches block-uniform.
//   - recon4_kernel: 192 threads, exactly one float4/thread/W-row (768/4).
//     4x fewer load instructions, 16B/lane coalescing (G13).
//   - Dense-fallback path vectorized (float4 enc vs LDS src): flagged row
//     ~100 us instead of ~1 ms (insurance; expected 0 rows).
// Round 9 (kept): GEMM with LDS-staged candidate flush (1 global atomic per
//   block-row); 608 us, MfmaUtil 29.3, WRITE 20 MB.
// Round 6-8 (kept): candidate-list algorithm; deterministic certification
//   (cnt in [33,CCAP], v*-MARGIN > guard) else exact dense fallback.
// Round 4 (kept): GEMM core 48KB dbuf, vmcnt(6), 2 barriers/K-step,
//   bounds(256,3), setprio, XCD swizzle. Round 3: split bf16, MARGIN+refine.
// ============================================================================

#define N_ROWS 4096
#define D_DIM  768
#define H_DIM  16384
#define M_TOT  8192
#define TOPK   32
#define MARGIN 1e-3f
#define SEL_CAP 40
#define AMB_CAP 64
#define CCAP   512
#define SCAP   24      // per (row, 128-col block) candidate cap
// cos filter: ~2.2 sigma (sigma = 1/sqrt(768) = 0.036). Row 33rd-largest
// cos ~ 0.104 (2.9 sigma). sim(0.08) = 2 - sqrt(1.84) = 0.643534.
#define THR_COS 0.08f
#define THR_SIM_GUARD 0.6436f

typedef __attribute__((ext_vector_type(8))) short short8;
typedef __attribute__((ext_vector_type(4))) float floatx4;

__device__ inline unsigned short bf16_rne(float f) {
    unsigned u = __float_as_uint(f);
    unsigned r = u + 0x7fffu + ((u >> 16) & 1u);
    return (unsigned short)(r >> 16);
}

__device__ inline void gload16(const unsigned short* g, unsigned short* l) {
    __builtin_amdgcn_global_load_lds(
        (const __attribute__((address_space(1))) void*)g,
        (__attribute__((address_space(3))) void*)l, 16, 0, 0);
}

// ---------------------------------------------------------------------------
// normalize rows of embv/embt/enc; emb -> bf16 hi+lo, enc -> bf16 hi only.
// First 64 blocks also zero cand_cnt+flag (2*M_TOT adjacent ints).
__global__ void split_all_kernel(const float* __restrict__ embv,
                                 const float* __restrict__ embt,
                                 const float* __restrict__ enc,
                                 unsigned short* __restrict__ Ahi,
                                 unsigned short* __restrict__ Alo,
                                 unsigned short* __restrict__ Bh,
                                 float* __restrict__ invA,
                                 float* __restrict__ invB,
                                 int* __restrict__ cntflag)
{
    int row = blockIdx.x;                  // 0..2N+H-1
    int tid = threadIdx.x;
    if (row < 64) {                        // 64*256 == 2*M_TOT exactly
        cntflag[row * 256 + tid] = 0;
    }
    const float* src;
    unsigned short *hi, *lo;
    float* invp;
    if (row < N_ROWS) {
        src = embv + (size_t)row * D_DIM;
        hi = Ahi + (size_t)row * D_DIM; lo = Alo + (size_t)row * D_DIM;
        invp = invA + row;
    } else if (row < 2 * N_ROWS) {
        int r = row - N_ROWS;
        src = embt + (size_t)r * D_DIM;
        hi = Ahi + (size_t)row * D_DIM; lo = Alo + (size_t)row * D_DIM;
        invp = invA + row;
    } else {
        int r = row - 2 * N_ROWS;
        src = enc + (size_t)r * D_DIM;
        hi = Bh + (size_t)r * D_DIM; lo = nullptr;
        invp = invB + r;
    }
    __shared__ float red[4];
    const float4* s4 = reinterpret_cast<const float4*>(src);
    float4 v = make_float4(0.f, 0.f, 0.f, 0.f);
    float ss = 0.f;
    if (tid < 192) {
        v = s4[tid];
        ss = v.x * v.x + v.y * v.y + v.z * v.z + v.w * v.w;
    }
    #pragma unroll
    for (int o = 32; o > 0; o >>= 1) ss += __shfl_down(ss, o);
    int wave = tid >> 6, lane = tid & 63;
    if (lane == 0) red[wave] = ss;
    __syncthreads();
    if (tid == 0) {
        float tot = red[0] + red[1] + red[2];
        red[0] = 1.f / fmaxf(sqrtf(tot), 1e-12f);
    }
    __syncthreads();
    float inv = red[0];
    if (tid == 0) *invp = inv;
    if (tid < 192) {
        float x[4] = {v.x * inv, v.y * inv, v.z * inv, v.w * inv};
        unsigned short hh[4], ll[4];
        #pragma unroll
        for (int t = 0; t < 4; t++) {
            hh[t] = bf16_rne(x[t]);
            float hf = __uint_as_float((unsigned)hh[t] << 16);
            ll[t] = bf16_rne(x[t] - hf);
        }
        ushort4 h4; h4.x = hh[0]; h4.y = hh[1]; h4.z = hh[2]; h4.w = hh[3];
        *reinterpret_cast<ushort4*>(hi + tid * 4) = h4;
        if (lo) {
            ushort4 l4; l4.x = ll[0]; l4.y = ll[1]; l4.z = ll[2]; l4.w = ll[3];
            *reinterpret_cast<ushort4*>(lo + tid * 4) = l4;
        }
    }
}

// ---------------------------------------------------------------------------
// 2-product split GEMM: cos = (Ahi+Alo) . Bh  (inputs pre-normalized)
// Round-4 pipeline core; Round-9 epilogue: LDS-staged candidate flush.
#define GBK 32
#define NTILE (D_DIM / GBK)   // 24

__global__ __launch_bounds__(256, 3)
void gemm_mfma_kernel(const unsigned short* __restrict__ Ahi,
                      const unsigned short* __restrict__ Alo,
                      const unsigned short* __restrict__ Bh,
                      int* __restrict__ cand_cnt,
                      int* __restrict__ cand_idx,
                      float* __restrict__ cand_val)
{
    __shared__ unsigned short sA[2][2][128 * GBK];
    __shared__ unsigned short sB[2][128 * GBK];

    int tid = threadIdx.x;
    int lane = tid & 63;
    int wave = tid >> 6;
    int wr = (wave >> 1) * 64;
    int wc = (wave & 1) * 64;
    int m = lane & 15;
    int q = lane >> 4;

    // XCD-aware bijective swizzle: grid = 128x64 = 8192 blocks, 8192 % 8 == 0.
    unsigned nwgx = gridDim.x;                        // 128
    unsigned lid = blockIdx.y * nwgx + blockIdx.x;
    unsigned cpx = (nwgx * gridDim.y) >> 3;           // 1024
    unsigned swz = (lid & 7u) * cpx + (lid >> 3);
    int bx = (int)(swz % nwgx);
    int by = (int)(swz / nwgx);

    int row0 = by * 128;
    int col0 = bx * 128;

    int p0 = tid, p1 = tid + 256;
    int r0 = ((p0 >> 5) << 3) | (p0 & 7), q0 = (p0 >> 3) & 3;
    int r1 = ((p1 >> 5) << 3) | (p1 & 7), q1 = (p1 >> 3) & 3;
    size_t aoff0 = (size_t)(row0 + r0) * D_DIM + q0 * 8;
    size_t aoff1 = (size_t)(row0 + r1) * D_DIM + q1 * 8;
    size_t boff0 = (size_t)(col0 + r0) * D_DIM + q0 * 8;
    size_t boff1 = (size_t)(col0 + r1) * D_DIM + q1 * 8;

    int am0 = wr + m;
    int bn0 = wc + m;
    int offA = ((am0 >> 3) << 8) + (q << 6) + ((am0 & 7) << 3);
    int offB = ((bn0 >> 3) << 8) + (q << 6) + ((bn0 & 7) << 3);

    floatx4 acc[4][4];
    #pragma unroll
    for (int i = 0; i < 4; i++)
        #pragma unroll
        for (int j = 0; j < 4; j++)
            acc[i][j] = (floatx4){0.f, 0.f, 0.f, 0.f};

    // 6 global_load_lds per stage (vmcnt unit)
    auto stage = [&](int t, int b) {
        int k0 = t * GBK;
        gload16(Ahi + aoff0 + k0, &sA[b][0][p0 * 8]);
        gload16(Ahi + aoff1 + k0, &sA[b][0][p1 * 8]);
        gload16(Alo + aoff0 + k0, &sA[b][1][p0 * 8]);
        gload16(Alo + aoff1 + k0, &sA[b][1][p1 * 8]);
        gload16(Bh + boff0 + k0, &sB[b][p0 * 8]);
        gload16(Bh + boff1 + k0, &sB[b][p1 * 8]);
    };

    auto compute = [&](int b) {
        short8 fah[4], fal[4], fbv[4];
        #pragma unroll
        for (int i = 0; i < 4; i++) {
            fah[i] = *(const short8*)&sA[b][0][offA + i * 512];
            fal[i] = *(const short8*)&sA[b][1][offA + i * 512];
        }
        #pragma unroll
        for (int j = 0; j < 4; j++)
            fbv[j] = *(const short8*)&sB[b][offB + j * 512];
        __builtin_amdgcn_s_setprio(1);
        #pragma unroll
        for (int j = 0; j < 4; j++) {
            #pragma unroll
            for (int i = 0; i < 4; i++) {
                acc[i][j] = __builtin_amdgcn_mfma_f32_16x16x32_bf16(fah[i], fbv[j], acc[i][j], 0, 0, 0);
                acc[i][j] = __builtin_amdgcn_mfma_f32_16x16x32_bf16(fal[i], fbv[j], acc[i][j], 0, 0, 0);
            }
        }
        __builtin_amdgcn_s_setprio(0);
    };

    // Round-4 pipeline: depth-1 dbuf, vmcnt(6) (tile t retires, t+1 stays in
    // flight), 2 barriers/K-step. Measured best (641 us vs 689 for 3-buf).
    stage(0, 0);
    int cur = 0;
    for (int t = 0; t < NTILE - 1; ++t) {
        stage(t + 1, cur ^ 1);
        asm volatile("s_waitcnt vmcnt(6)" ::: "memory");
        __builtin_amdgcn_s_barrier();
        __builtin_amdgcn_sched_barrier(0);
        compute(cur);
        __builtin_amdgcn_sched_barrier(0);
        __builtin_amdgcn_s_barrier();
        cur ^= 1;
    }
    asm volatile("s_waitcnt vmcnt(0)" ::: "memory");
    __builtin_amdgcn_s_barrier();
    __builtin_amdgcn_sched_barrier(0);
    compute(cur);

    // ---- Epilogue: LDS-staged candidate flush (round-9, measured good) ----
    __syncthreads();                        // all waves done reading sA
    int*   s_rcnt = (int*)(&sA[0][0][0]);   // 128 ints
    int*   s_ridx = s_rcnt + 128;           // 128*SCAP ints
    float* s_rval = (float*)(s_ridx + 128 * SCAP);   // 128*SCAP floats
    if (tid < 128) s_rcnt[tid] = 0;
    __syncthreads();

    #pragma unroll
    for (int i = 0; i < 4; i++) {
        #pragma unroll
        for (int r = 0; r < 4; r++) {
            int lrow = wr + i * 16 + q * 4 + r;          // 0..127
            #pragma unroll
            for (int j = 0; j < 4; j++) {
                float cosv = acc[i][j][r];
                if (cosv >= THR_COS) {
                    int s = atomicAdd(&s_rcnt[lrow], 1);  // LDS atomic, cheap
                    if (s < SCAP) {
                        s_ridx[lrow * SCAP + s] = wc + m + j * 16;  // 0..127
                        s_rval[lrow * SCAP + s] = cosv;
                    }
                }
            }
        }
    }
    __syncthreads();

    if (tid < 128) {
        int c = s_rcnt[tid];
        if (c > 0) {
            int grow = row0 + tid;
            int wcnt = (c > SCAP) ? SCAP : c;
            // overflow (impossible statistically) forces cnt > CCAP -> exact path
            int addc = (c > SCAP) ? (CCAP + 1) : c;
            int base = atomicAdd(&cand_cnt[grow], addc);  // 1 atomic per (blk,row)
            for (int s2 = 0; s2 < wcnt; ++s2) {
                int slot = base + s2;
                if (slot < CCAP) {
                    cand_idx[(size_t)grow * CCAP + slot] = col0 + s_ridx[tid * SCAP + s2];
                    cand_val[(size_t)grow * CCAP + slot] = s_rval[tid * SCAP + s2];
                }
            }
        }
    }
}

// ---------------------------------------------------------------------------
// FUSED per-row pipeline: zero own latent row -> candidate select -> classify
// -> inline refine (amb, in LDS) OR inline exact dense fallback.
// All branch conditions are block-uniform (cnt, vs, samb, skept from LDS
// after barriers) => no divergent barriers.
__global__ __launch_bounds__(256)
void select_finalize_kernel(const int* __restrict__ cand_cnt,
                            const int* __restrict__ cand_idx,
                            const float* __restrict__ cand_val,
                            const float* __restrict__ embv,
                            const float* __restrict__ embt,
                            const float* __restrict__ enc,
                            const float* __restrict__ invA,
                            const float* __restrict__ invB,
                            float* __restrict__ latent,
                            int* __restrict__ sel_cnt,
                            int* __restrict__ sel_idx,
                            float* __restrict__ sel_val)
{
    int row = blockIdx.x;
    int tid = threadIdx.x;
    float* v = latent + (size_t)row * H_DIM;

    // zero own latent row (mandatory output bytes)
    floatx4* vw = (floatx4*)v;
    floatx4 z = (floatx4){0.f, 0.f, 0.f, 0.f};
    #pragma unroll
    for (int k = 0; k < 16; k++)
        __builtin_nontemporal_store(z, &vw[tid + 256 * k]);

    int cnt = cand_cnt[row];

    __shared__ float sv[CCAP];
    __shared__ int   si[CCAP];
    __shared__ int   s_amb[AMB_CAP];
    __shared__ float ex[AMB_CAP];
    __shared__ float ssrc[D_DIM];
    __shared__ unsigned hist[256];
    __shared__ unsigned s_prefix;
    __shared__ int svstar, skept, samb, s_k, s_cnt2, evs, kc;

    bool bad = (cnt > CCAP || cnt < TOPK + 1);
    float vs = 0.f;
    if (!bad) {
        for (int c = tid; c < cnt; c += 256) {
            float cosv = cand_val[(size_t)row * CCAP + c];
            sv[c] = 2.f - sqrtf(fmaxf(2.f - 2.f * cosv, 0.f));   // same fp32 ops
            si[c] = cand_idx[(size_t)row * CCAP + c];
        }
        if (tid == 0) { svstar = 0x7FFFFFFF; skept = 0; samb = 0; }
        __syncthreads();
        // v* = 33rd largest candidate sim (== 33rd overall: every candidate
        // >= every non-candidate and cnt >= 33). Slot-order tie-break;
        // boundary ties land in the ambiguous band, refined exactly.
        for (int c = tid; c < cnt; c += 256) {
            float a = sv[c];
            int g = 0;
            for (int j = 0; j < cnt; j++) {
                float aj = sv[j];
                g += (aj > a || (aj == a && j < c)) ? 1 : 0;
            }
            if (g <= TOPK) atomicMin(&svstar, __float_as_int(a));
        }
        __syncthreads();
        vs = __int_as_float(svstar);
        // Certify static filter: every non-candidate sim < THR_SIM_GUARD
        // < vs - MARGIN => certain drop under the round-3 rule.
        bad = (vs - MARGIN <= THR_SIM_GUARD);
    }

    const float* src = (row < N_ROWS) ? embv + (size_t)row * D_DIM
                                      : embt + (size_t)(row - N_ROWS) * D_DIM;
    float ia = invA[row];

    if (bad) {
        // ---------------- inline exact dense fallback (expected 0 rows) ----
        for (int d = tid; d < D_DIM; d += 256) ssrc[d] = src[d];
        __syncthreads();
        const floatx4* s4 = (const floatx4*)ssrc;
        for (int h = tid; h < H_DIM; h += 256) {
            const floatx4* w4 = (const floatx4*)(enc + (size_t)h * D_DIM);
            float d = 0.f;
            for (int t = 0; t < D_DIM / 4; t++) {
                floatx4 a = s4[t], b = w4[t];
                d += a.x * b.x + a.y * b.y + a.z * b.z + a.w * b.w;
            }
            float cosv = d * ia * invB[h];
            v[h] = 2.f - sqrtf(fmaxf(2.f - 2.f * cosv, 0.f));
        }
        __syncthreads();
        // radix-select the 33rd largest (sims >= 0 -> raw bits monotone)
        int k = TOPK + 1;
        unsigned prefix = 0;
        for (int shift = 24; shift >= 0; shift -= 8) {
            hist[tid] = 0;
            __syncthreads();
            unsigned pmask = (shift == 24) ? 0u : (0xFFFFFFFFu << (shift + 8));
            for (int i = tid; i < H_DIM; i += 256) {
                unsigned u = __float_as_uint(v[i]);
                if ((u & pmask) == prefix)
                    atomicAdd(&hist[(u >> shift) & 255u], 1u);
            }
            __syncthreads();
            if (tid == 0) {
                int c = 0, b = 255;
                for (; b >= 0; b--) {
                    c += (int)hist[b];
                    if (c >= k) break;
                }
                if (b < 0) b = 0;
                s_prefix = prefix | ((unsigned)b << shift);
                s_k = k - (c - (int)hist[b]);
            }
            __syncthreads();
            prefix = s_prefix;
            k = s_k;
            __syncthreads();
        }
        float thres = __uint_as_float(prefix);
        if (tid == 0) s_cnt2 = 0;
        __syncthreads();
        for (int i = tid; i < H_DIM; i += 256) {
            float x = v[i];
            bool keep = (x > thres);
            v[i] = keep ? x : 0.f;
            if (keep) {
                int slot = atomicAdd(&s_cnt2, 1);
                if (slot < SEL_CAP) {
                    sel_idx[(size_t)row * SEL_CAP + slot] = i;
                    sel_val[(size_t)row * SEL_CAP + slot] = x;
                }
            }
        }
        __syncthreads();
        if (tid == 0) sel_cnt[row] = (s_cnt2 > SEL_CAP) ? SEL_CAP : s_cnt2;
        return;
    }

    // ---------------- classify (zero-stores drained by prior barriers) -----
    for (int c = tid; c < cnt; c += 256) {
        float f = sv[c];
        int idx = si[c];
        if (f > vs + MARGIN) {
            int s = atomicAdd(&skept, 1);
            sel_idx[(size_t)row * SEL_CAP + s] = idx;
            sel_val[(size_t)row * SEL_CAP + s] = f;
            v[idx] = f;
        } else if (f >= vs - MARGIN) {
            int s = atomicAdd(&samb, 1);
            if (s < AMB_CAP) s_amb[s] = idx;
        }
    }
    __syncthreads();
    int m_ = skept;
    int s_ = min(samb, AMB_CAP);
    int need = TOPK - m_;
    if (s_ == 0 || need <= 0) {
        if (tid == 0) sel_cnt[row] = m_;
        return;
    }

    // ---------------- inline refine (exact dots for ambiguous entries) -----
    int wave = tid >> 6, lane = tid & 63;
    for (int a = wave; a < s_; a += 4) {
        int h = s_amb[a];
        const float* w = enc + (size_t)h * D_DIM;
        float d = 0.f;
        for (int t = lane; t < D_DIM; t += 64) d += src[t] * w[t];
        #pragma unroll
        for (int o = 32; o > 0; o >>= 1) d += __shfl_down(d, o);
        if (lane == 0) {
            float cosv = d * ia * invB[h];
            ex[a] = 2.f - sqrtf(fmaxf(2.f - 2.f * cosv, 0.f));
        }
    }
    if (tid == 0) { evs = 0x7FFFFFFF; kc = 0; }
    __syncthreads();
    if (tid < s_) {
        float mya = fabsf(ex[tid]);
        int g = 0;
        for (int j = 0; j < s_; j++) {
            float aj = fabsf(ex[j]);
            g += (aj > mya || (aj == mya && j < tid)) ? 1 : 0;
        }
        if (g <= need) atomicMin(&evs, __float_as_int(mya));
    }
    __syncthreads();
    float ep = __int_as_float(evs);
    if (tid < s_) {
        int idx = s_amb[tid];
        float e = ex[tid];
        if (fabsf(e) > ep) {
            int sl = atomicAdd(&kc, 1);
            v[idx] = e;
            sel_idx[(size_t)row * SEL_CAP + m_ + sl] = idx;
            sel_val[(size_t)row * SEL_CAP + m_ + sl] = e;
        }
    }
    __syncthreads();
    if (tid == 0) sel_cnt[row] = m_ + kc;
}

// ---------------------------------------------------------------------------
__global__ void transpose_kernel(const float* __restrict__ Wv,
                                 const float* __restrict__ Wt,
                                 float* __restrict__ WvT,
                                 float* __restrict__ WtT)
{
    int z = blockIdx.z;
    const float* W = z ? Wt : Wv;
    float* WT = z ? WtT : WvT;
    __shared__ float tile[32][33];
    int tx = threadIdx.x & 31;
    int ty = threadIdx.x >> 5;
    int h0 = blockIdx.x * 32;
    int d0 = blockIdx.y * 32;
    #pragma unroll
    for (int t = 0; t < 4; t++)
        tile[ty + t * 8][tx] = W[(size_t)(d0 + ty + t * 8) * H_DIM + h0 + tx];
    __syncthreads();
    #pragma unroll
    for (int t = 0; t < 4; t++)
        WT[(size_t)(h0 + ty + t * 8) * D_DIM + d0 + tx] = tile[tx][ty + t * 8];
}

// ---------------------------------------------------------------------------
// recon, vectorized: 192 threads, one float4 per thread per W^T row (768/4).
__global__ __launch_bounds__(192)
void recon4_kernel(const float* __restrict__ WvT,
                   const float* __restrict__ WtT,
                   const float* __restrict__ bv,
                   const float* __restrict__ bt,
                   const int* __restrict__ sel_cnt,
                   const int* __restrict__ sel_idx,
                   const float* __restrict__ sel_val,
                   float* __restrict__ out)
{
    int n = blockIdx.x;
    int z = blockIdx.y;
    int row = z * N_ROWS + n;
    const float* W = z ? WtT : WvT;
    const float* bias = z ? bt : bv;
    float* o = out + (size_t)z * N_ROWS * D_DIM + (size_t)n * D_DIM;

    __shared__ int s_idx[SEL_CAP];
    __shared__ float s_val[SEL_CAP];
    __shared__ int s_cnt;
    int tid = threadIdx.x;
    if (tid == 0) s_cnt = sel_cnt[row];
    __syncthreads();
    int cnt = s_cnt;
    if (tid < cnt) {
        s_idx[tid] = sel_idx[(size_t)row * SEL_CAP + tid];
        s_val[tid] = sel_val[(size_t)row * SEL_CAP + tid];
    }
    __syncthreads();

    float4 acc = reinterpret_cast<const float4*>(bias)[tid];
    for (int j = 0; j < cnt; j++) {
        float4 w = reinterpret_cast<const float4*>(W + (size_t)s_idx[j] * D_DIM)[tid];
        float vv = s_val[j];
        acc.x += vv * w.x; acc.y += vv * w.y;
        acc.z += vv * w.z; acc.w += vv * w.w;
    }
    reinterpret_cast<float4*>(o)[tid] = acc;
}

// ---------------------------------------------------------------------------
// general recon (legacy path only)
__global__ void recon_kernel(const float* __restrict__ Wv_,
                             const float* __restrict__ Wt_,
                             const float* __restrict__ bv,
                             const float* __restrict__ bt,
                             const int* __restrict__ sel_cnt,
                             const int* __restrict__ sel_idx,
                             const float* __restrict__ sel_val,
                             long sh, long sd,
                             float* __restrict__ out)
{
    int n = blockIdx.x;
    int z = blockIdx.y;
    int row = z * N_ROWS + n;
    const float* W = z ? Wt_ : Wv_;
    const float* bias = z ? bt : bv;
    float* o = out + (size_t)z * N_ROWS * D_DIM + (size_t)n * D_DIM;

    __shared__ int s_idx[SEL_CAP];
    __shared__ float s_val[SEL_CAP];
    __shared__ int s_cnt;
    int tid = threadIdx.x;
    if (tid == 0) s_cnt = sel_cnt[row];
    __syncthreads();
    int cnt = s_cnt;
    if (tid < cnt) {
        s_idx[tid] = sel_idx[(size_t)row * SEL_CAP + tid];
        s_val[tid] = sel_val[(size_t)row * SEL_CAP + tid];
    }
    __syncthreads();

    for (int d = tid; d < D_DIM; d += 256) {
        float acc = bias[d];
        for (int j = 0; j < cnt; j++)
            acc += s_val[j] * W[(size_t)s_idx[j] * sh + (size_t)d * sd];
        o[d] = acc;
    }
}

// ============================ LEGACY FALLBACK ==============================
__global__ void row_invnorm_kernel(const float* __restrict__ x,
                                   float* __restrict__ inv, int rows) {
    int row = blockIdx.x * 4 + (threadIdx.x >> 6);
    int lane = threadIdx.x & 63;
    if (row >= rows) return;
    const float4* p = reinterpret_cast<const float4*>(x + (size_t)row * D_DIM);
    float ss = 0.f;
    #pragma unroll
    for (int i = 0; i < 3; i++) {
        float4 v = p[lane + i * 64];
        ss += v.x * v.x + v.y * v.y + v.z * v.z + v.w * v.w;
    }
    #pragma unroll
    for (int off = 32; off > 0; off >>= 1) ss += __shfl_down(ss, off);
    if (lane == 0) inv[row] = 1.f / fmaxf(sqrtf(ss), 1e-12f);
}

#define BM 128
#define BN 128
#define BK 16
__global__ __launch_bounds__(256)
void gemm_sim_kernel(const float* __restrict__ embv,
                     const float* __restrict__ embt,
                     const float* __restrict__ enc,
                     const float* __restrict__ inv_emb,
                     const float* __restrict__ inv_enc,
                     float* __restrict__ latent)
{
    int z = blockIdx.z;
    const float* A = z ? embt : embv;
    const float* invA = inv_emb + z * N_ROWS;
    float* C = latent + (size_t)z * N_ROWS * H_DIM;
    __shared__ float As[BK][BM + 4];
    __shared__ float Bs[BK][BN + 4];
    int tid = threadIdx.x;
    int tx = tid & 15, ty = tid >> 4;
    int row0 = blockIdx.y * BM, col0 = blockIdx.x * BN;
    float acc[8][8];
    #pragma unroll
    for (int i = 0; i < 8; i++)
        #pragma unroll
        for (int j = 0; j < 8; j++) acc[i][j] = 0.f;
    for (int k0 = 0; k0 < D_DIM; k0 += BK) {
        #pragma unroll
        for (int t = 0; t < 2; t++) {
            int idx = t * 256 + tid;
            int r = idx >> 2, c4 = idx & 3;
            float4 va = *reinterpret_cast<const float4*>(
                A + (size_t)(row0 + r) * D_DIM + k0 + c4 * 4);
            As[c4 * 4 + 0][r] = va.x; As[c4 * 4 + 1][r] = va.y;
            As[c4 * 4 + 2][r] = va.z; As[c4 * 4 + 3][r] = va.w;
            float4 vb = *reinterpret_cast<const float4*>(
                enc + (size_t)(col0 + r) * D_DIM + k0 + c4 * 4);
            Bs[c4 * 4 + 0][r] = vb.x; Bs[c4 * 4 + 1][r] = vb.y;
            Bs[c4 * 4 + 2][r] = vb.z; Bs[c4 * 4 + 3][r] = vb.w;
        }
        __syncthreads();
        #pragma unroll
        for (int kk = 0; kk < BK; kk++) {
            float a[8], b[8];
            *reinterpret_cast<float4*>(&a[0]) = *reinterpret_cast<const float4*>(&As[kk][ty * 8]);
            *reinterpret_cast<float4*>(&a[4]) = *reinterpret_cast<const float4*>(&As[kk][ty * 8 + 4]);
            *reinterpret_cast<float4*>(&b[0]) = *reinterpret_cast<const float4*>(&Bs[kk][tx * 8]);
            *reinterpret_cast<float4*>(&b[4]) = *reinterpret_cast<const float4*>(&Bs[kk][tx * 8 + 4]);
            #pragma unroll
            for (int i = 0; i < 8; i++)
                #pragma unroll
                for (int j = 0; j < 8; j++)
                    acc[i][j] = fmaf(a[i], b[j], acc[i][j]);
        }
        __syncthreads();
    }
    #pragma unroll
    for (int i = 0; i < 8; i++) {
        int n = row0 + ty * 8 + i;
        float sa = invA[n];
        float* Crow = C + (size_t)n * H_DIM + col0 + tx * 8;
        float tmp[8];
        #pragma unroll
        for (int j = 0; j < 8; j++) {
            float cosv = acc[i][j] * sa * inv_enc[col0 + tx * 8 + j];
            tmp[j] = 2.f - sqrtf(fmaxf(2.f - 2.f * cosv, 0.f));
        }
        float4 o0 = {tmp[0], tmp[1], tmp[2], tmp[3]};
        float4 o1 = {tmp[4], tmp[5], tmp[6], tmp[7]};
        *reinterpret_cast<float4*>(Crow) = o0;
        *reinterpret_cast<float4*>(Crow + 4) = o1;
    }
}

__global__ void legacy_select_kernel(float* __restrict__ latent,
                                     const int* __restrict__ topk_p,
                                     int* __restrict__ sel_cnt,
                                     int* __restrict__ sel_idx,
                                     float* __restrict__ sel_val)
{
    int row = blockIdx.x;
    float* v = latent + (size_t)row * H_DIM;
    int tid = threadIdx.x;
    __shared__ unsigned hist[256];
    __shared__ unsigned s_prefix;
    __shared__ int s_k;
    __shared__ int s_cnt;
    int k = topk_p[0] + 1;
    unsigned prefix = 0;
    for (int shift = 24; shift >= 0; shift -= 8) {
        hist[tid] = 0;
        __syncthreads();
        unsigned pmask = (shift == 24) ? 0u : (0xFFFFFFFFu << (shift + 8));
        for (int i = tid; i < H_DIM; i += 256) {
            unsigned u = __float_as_uint(v[i]) & 0x7FFFFFFFu;
            if ((u & pmask) == prefix)
                atomicAdd(&hist[(u >> shift) & 255u], 1u);
        }
        __syncthreads();
        if (tid == 0) {
            int c = 0, b = 255;
            for (; b >= 0; b--) {
                c += (int)hist[b];
                if (c >= k) break;
            }
            if (b < 0) b = 0;
            s_prefix = prefix | ((unsigned)b << shift);
            s_k = k - (c - (int)hist[b]);
        }
        __syncthreads();
        prefix = s_prefix;
        k = s_k;
        __syncthreads();
    }
    float thres = __uint_as_float(prefix);
    if (tid == 0) s_cnt = 0;
    __syncthreads();
    for (int i = tid; i < H_DIM; i += 256) {
        float x = v[i];
        bool keep = (fabsf(x) > thres);
        v[i] = keep ? x : 0.f;
        if (keep) {
            int slot = atomicAdd(&s_cnt, 1);
            if (slot < SEL_CAP) {
                sel_idx[(size_t)row * SEL_CAP + slot] = i;
                sel_val[(size_t)row * SEL_CAP + slot] = x;
            }
        }
    }
    __syncthreads();
    if (tid == 0) sel_cnt[row] = (s_cnt > SEL_CAP) ? SEL_CAP : s_cnt;
}

// ---------------------------------------------------------------------------
extern "C" void kernel_launch(void* const* d_in, const int* in_sizes, int n_in,
                              void* d_out, int out_size, void* d_ws, size_t ws_size,
                              hipStream_t stream) {
    const float* embv = (const float*)d_in[0];
    const float* embt = (const float*)d_in[1];
    const float* enc  = (const float*)d_in[2];
    const float* Wv   = (const float*)d_in[3];
    const float* bv   = (const float*)d_in[4];
    const float* Wt   = (const float*)d_in[5];
    const float* bt   = (const float*)d_in[6];
    const int* topk   = (const int*)d_in[7];
    float* out = (float*)d_out;

    float* recon_out = out;                              // [2][N][D]
    float* latent = out + (size_t)2 * N_ROWS * D_DIM;    // [2][N][H]

    char* ws = (char*)d_ws;
    size_t off = 0;
    float* invA = (float*)(ws + off);            off += (size_t)M_TOT * 4;
    float* invB = (float*)(ws + off);            off += (size_t)H_DIM * 4;
    int*   sel_cnt = (int*)(ws + off);           off += (size_t)M_TOT * 4;
    int*   amb_cnt = (int*)(ws + off);           off += (size_t)M_TOT * 4;   // unused (kept layout)
    int*   sel_idx = (int*)(ws + off);           off += (size_t)M_TOT * SEL_CAP * 4;
    float* sel_val = (float*)(ws + off);         off += (size_t)M_TOT * SEL_CAP * 4;
    int*   amb_idx = (int*)(ws + off);           off += (size_t)M_TOT * AMB_CAP * 4;  // unused
    int*   cand_cnt = (int*)(ws + off);          off += (size_t)M_TOT * 4;   // cnt+flag adjacent
    int*   flag     = (int*)(ws + off);          off += (size_t)M_TOT * 4;   // unused
    unsigned short* Ahi = (unsigned short*)(ws + off); off += (size_t)M_TOT * D_DIM * 2;
    unsigned short* Alo = (unsigned short*)(ws + off); off += (size_t)M_TOT * D_DIM * 2;
    unsigned short* Bh  = (unsigned short*)(ws + off); off += (size_t)H_DIM * D_DIM * 2;
    size_t core_need = off;
    (void)amb_cnt; (void)amb_idx; (void)flag;

    // candidate buffers alias the WvT/WtT region: cand is dead before
    // transpose_kernel runs (reader: select_finalize only).
    int*   cand_idx = (int*)(ws + off);
    float* cand_val = (float*)(ws + off + (size_t)M_TOT * CCAP * 4);
    size_t cand_bytes = (size_t)M_TOT * CCAP * 8;             // 33.5 MB
    float* WvT = (float*)(ws + off);
    float* WtT = WvT + (size_t)D_DIM * H_DIM;
    size_t trans_bytes = (size_t)2 * D_DIM * H_DIM * 4;       // 100 MB
    (void)cand_bytes;

    if (ws_size >= core_need + trans_bytes) {
        // fast path (requires the transpose region; cand aliases it safely)
        split_all_kernel<<<2 * N_ROWS + H_DIM, 256, 0, stream>>>(
            embv, embt, enc, Ahi, Alo, Bh, invA, invB, cand_cnt);

        gemm_mfma_kernel<<<dim3(H_DIM / 128, M_TOT / 128), 256, 0, stream>>>(
            Ahi, Alo, Bh, cand_cnt, cand_idx, cand_val);

        select_finalize_kernel<<<M_TOT, 256, 0, stream>>>(
            cand_cnt, cand_idx, cand_val, embv, embt, enc, invA, invB,
            latent, sel_cnt, sel_idx, sel_val);

        transpose_kernel<<<dim3(H_DIM / 32, D_DIM / 32, 2), 256, 0, stream>>>(
            Wv, Wt, WvT, WtT);

        recon4_kernel<<<dim3(N_ROWS, 2), 192, 0, stream>>>(
            WvT, WtT, bv, bt, sel_cnt, sel_idx, sel_val, recon_out);
    } else {
        // legacy all-fp32 path (small workspace)
        size_t o2 = 0;
        float* inv_enc = (float*)(ws + o2); o2 += (size_t)H_DIM * 4;
        float* inv_emb = (float*)(ws + o2); o2 += (size_t)2 * N_ROWS * 4;
        int*   l_cnt = (int*)(ws + o2);     o2 += (size_t)2 * N_ROWS * 4;
        int*   l_idx = (int*)(ws + o2);     o2 += (size_t)2 * N_ROWS * SEL_CAP * 4;
        float* l_val = (float*)(ws + o2);   o2 += (size_t)2 * N_ROWS * SEL_CAP * 4;
        row_invnorm_kernel<<<H_DIM / 4, 256, 0, stream>>>(enc, inv_enc, H_DIM);
        row_invnorm_kernel<<<N_ROWS / 4, 256, 0, stream>>>(embv, inv_emb, N_ROWS);
        row_invnorm_kernel<<<N_ROWS / 4, 256, 0, stream>>>(embt, inv_emb + N_ROWS, N_ROWS);
        dim3 g(H_DIM / BN, N_ROWS / BM, 2);
        gemm_sim_kernel<<<g, 256, 0, stream>>>(embv, embt, enc, inv_emb, inv_enc, latent);
        legacy_select_kernel<<<2 * N_ROWS, 256, 0, stream>>>(latent, topk, l_cnt, l_idx, l_val);
        recon_kernel<<<dim3(N_ROWS, 2), 256, 0, stream>>>(
            Wv, Wt, bv, bt, l_cnt, l_idx, l_val, 1L, (long)H_DIM, recon_out);
    }
}